// Round 13
// baseline (240.695 us; speedup 1.0000x reference)
//
#include <hip/hip_runtime.h>

typedef __bf16 bf16x8 __attribute__((ext_vector_type(8)));
typedef float f32x4 __attribute__((ext_vector_type(4)));

#define MFMA_BF16 __builtin_amdgcn_mfma_f32_16x16x32_bf16

static constexpr int T_ = 2048;
static constexpr int C_ = 1024;
static constexpr int H_ = 16;
static constexpr int KVH_ = 4;
static constexpr int D_ = 64;
static constexpr float INVLN2_ = 1.4426950408889634f;
static constexpr float SCALE2_ = 0.125f * 1.4426950408889634f;
// Fixed softmax shift: scores = qk*SCALE + (ci-cj) with ci-cj<=0 and
// |qk|*SCALE <= 8 (rmsnorm'd) -> row max in [-8, 8]. Shift by 10: exp args
// <= -2 (no overflow); row max term >= exp(-18) (no 0/0). Constant shift =>
// arbitrary j-partials combine by plain summation (no max bookkeeping).
static constexpr float MSHIFT_ = 10.0f;

// Uniform attention work: unit = (h, ib, jt), W = 16*528 = 8448.
// Grid = 1024 blocks exactly (4/CU); groups of 4 blocks cover 33 units
// as 9+8+8+8. (R12 lesson: this structure needs >=16 waves/CU of BLOCK
// parallelism; per-wave ILP (GQA-fusion) does not substitute -- v9 cut LDS
// ops 2.4x and still lost 42% at 8 waves/CU.)
static constexpr int UPH_ = 528;
static constexpr int NBLK_ = 1024;
static constexpr int LDP_ = 76;   // LDS row stride: bank r*6%32, 16 distinct
                                  // rows -> conflict-free (verified in R12:
                                  // SQ_LDS_BANK_CONFLICT = 0 at stride 76)

// ---------------------------------------------------------------------------
// cvt + gates FUSED (R11). Blocks [0,3344): fp32->bf16 + accumulator zero.
// Blocks [3344,3856): gates with wl staged coalesced into LDS + transposed.
// ---------------------------------------------------------------------------
__device__ inline void cvt8(__bf16* dst, const float* src) {
  float4 a = *(const float4*)src;
  float4 b = *(const float4*)(src + 4);
  bf16x8 r;
  r[0] = (__bf16)a.x; r[1] = (__bf16)a.y; r[2] = (__bf16)a.z; r[3] = (__bf16)a.w;
  r[4] = (__bf16)b.x; r[5] = (__bf16)b.y; r[6] = (__bf16)b.z; r[7] = (__bf16)b.w;
  *(bf16x8*)dst = r;
}

__global__ __launch_bounds__(256) void cvtgates_kernel(
    const float* __restrict__ x,  const float* __restrict__ wq,
    const float* __restrict__ wk, const float* __restrict__ wv,
    const float* __restrict__ wo, const float* __restrict__ wl,
    __bf16* __restrict__ xb,  __bf16* __restrict__ wqb,
    __bf16* __restrict__ wkb, __bf16* __restrict__ wvb,
    __bf16* __restrict__ wob, float* __restrict__ zbuf,
    const float* __restrict__ fw, const float* __restrict__ fb,
    float* __restrict__ logf)
{
  __shared__ float wlds[16 * 1024];     // [h][c] transposed wl (64 KB)
  if (blockIdx.x >= 3344) {
    const int t0 = (blockIdx.x - 3344) * 4;
    const int tid = threadIdx.x, w = tid >> 6, lane = tid & 63;
    const float4* wl4 = (const float4*)wl;
#pragma unroll
    for (int j = 0; j < 16; ++j) {
      float4 f = wl4[j * 256 + tid];
      int e = (j * 256 + tid) * 4;
      int c = e >> 4, h0 = e & 15;
      wlds[(h0 + 0) * 1024 + c] = f.x;
      wlds[(h0 + 1) * 1024 + c] = f.y;
      wlds[(h0 + 2) * 1024 + c] = f.z;
      wlds[(h0 + 3) * 1024 + c] = f.w;
    }
    float xv[4][16];
#pragma unroll
    for (int tt = 0; tt < 4; ++tt)
#pragma unroll
      for (int i = 0; i < 16; ++i)
        xv[tt][i] = x[(size_t)(t0 + tt) * C_ + i * 64 + lane];
    __syncthreads();
#pragma unroll
    for (int u = 0; u < 4; ++u) {
      int h = w * 4 + u;
      float wlr[16], fwr[16];
#pragma unroll
      for (int i = 0; i < 16; ++i) {
        wlr[i] = wlds[h * 1024 + i * 64 + lane];
        fwr[i] = fw[(size_t)h * C_ + i * 64 + lane];
      }
#pragma unroll
      for (int tt = 0; tt < 4; ++tt) {
        float s1 = 0.f, s2 = 0.f;
#pragma unroll
        for (int i = 0; i < 16; ++i) {
          s1 += xv[tt][i] * wlr[i];
          s2 += xv[tt][i] * fwr[i];
        }
        for (int m = 32; m; m >>= 1) {
          s1 += __shfl_xor(s1, m);
          s2 += __shfl_xor(s2, m);
        }
        if (lane == 0) {
          float lam = (s1 > 0.f ? s1 : expm1f(s1)) + 1.0f;
          float logit = (s2 + fb[h]) * lam;
          float ls = (logit >= 0.f) ? -log1pf(expf(-logit))
                                    : (logit - log1pf(expf(logit)));
          logf[(size_t)h * T_ + t0 + tt] = ls / (lam + 1e-3f);
        }
      }
    }
    return;
  }
  size_t i8 = ((size_t)blockIdx.x * 256 + threadIdx.x) * 8;
  // segment boundaries (elements): x 2097152 | Wq 1048576 | Wk 262144 |
  // Wv 262144 | Wo 1048576 | zero 2129920
  if (i8 < 2097152)       cvt8(xb  + i8,            x  + i8);
  else if (i8 < 3145728)  cvt8(wqb + (i8-2097152),  wq + (i8-2097152));
  else if (i8 < 3407872)  cvt8(wkb + (i8-3145728),  wk + (i8-3145728));
  else if (i8 < 3670016)  cvt8(wvb + (i8-3407872),  wv + (i8-3407872));
  else if (i8 < 4718592)  cvt8(wob + (i8-3670016),  wo + (i8-3670016));
  else {
    size_t z = i8 - 4718592;
    if (z < 2129920) {
      float4 zz = {0.f, 0.f, 0.f, 0.f};
      *(float4*)(zbuf + z) = zz;
      *(float4*)(zbuf + z + 4) = zz;
    }
  }
}

// ---------------------------------------------------------------------------
// GEMM: out[M,N] = A[M,K] @ B[N,K]^T, all bf16, fp32 out. BM=64, 384 blocks.
// ---------------------------------------------------------------------------
template <int BM>
__global__ __launch_bounds__(256) void gemm_bt_kernel(
    const __bf16* __restrict__ A, int K, int N,
    const __bf16* __restrict__ B0, int e0,
    const __bf16* __restrict__ B1, int e1,
    const __bf16* __restrict__ B2,
    float* __restrict__ outF)
{
  __shared__ __bf16 la[BM * 40];
  __shared__ __bf16 lb[128 * 40];
  const int m0 = blockIdx.y * BM;
  const int n0 = blockIdx.x * 128;
  const __bf16* Bs; int nrel;
  if (n0 < e0)      { Bs = B0; nrel = n0; }
  else if (n0 < e1) { Bs = B1; nrel = n0 - e0; }
  else              { Bs = B2; nrel = n0 - e1; }
  const int tid = threadIdx.x;
  const int arow = tid >> 2, acol = (tid & 3) * 8;
  const __bf16* ap = A  + (size_t)(m0   + arow) * K + acol;
  const __bf16* bp = Bs + (size_t)(nrel + arow) * K + acol;
  const int w = tid >> 6, lane = tid & 63, lq = lane >> 4, ln = lane & 15;
  const int wm = (w >> 1) * (BM / 2), wn = (w & 1) * 64;
  constexpr int FM = BM / 32;
  f32x4 acc[FM][4] = {};
  for (int k0 = 0; k0 < K; k0 += 32) {
    bf16x8 a0 = *(const bf16x8*)(ap + k0);
    bf16x8 a1{};
    if (BM == 128) a1 = *(const bf16x8*)(ap + (size_t)64 * K + k0);
    bf16x8 b0 = *(const bf16x8*)(bp + k0);
    bf16x8 b1 = *(const bf16x8*)(bp + (size_t)64 * K + k0);
    __syncthreads();
    *(bf16x8*)(la + arow * 40 + acol) = a0;
    if (BM == 128) *(bf16x8*)(la + (arow + 64) * 40 + acol) = a1;
    *(bf16x8*)(lb + arow * 40 + acol) = b0;
    *(bf16x8*)(lb + (arow + 64) * 40 + acol) = b1;
    __syncthreads();
    bf16x8 af[FM], bfr[4];
#pragma unroll
    for (int i = 0; i < FM; ++i)
      af[i] = *(const bf16x8*)(la + (wm + i * 16 + ln) * 40 + lq * 8);
#pragma unroll
    for (int j = 0; j < 4; ++j)
      bfr[j] = *(const bf16x8*)(lb + (wn + j * 16 + ln) * 40 + lq * 8);
#pragma unroll
    for (int i = 0; i < FM; ++i)
#pragma unroll
      for (int j = 0; j < 4; ++j)
        acc[i][j] = MFMA_BF16(af[i], bfr[j], acc[i][j], 0, 0, 0);
  }
#pragma unroll
  for (int i = 0; i < FM; ++i)
#pragma unroll
    for (int j = 0; j < 4; ++j)
#pragma unroll
      for (int r = 0; r < 4; ++r) {
        int row = m0 + wm + i * 16 + lq * 4 + r;
        int col = n0 + wn + j * 16 + ln;
        outF[(size_t)row * N + col] = acc[i][j][r];
      }
}

// ---------------------------------------------------------------------------
// Output GEMM with FUSED attention finalize: A[t][c] = oacc[h][t][d]/ls[h][t]
// ---------------------------------------------------------------------------
__global__ __launch_bounds__(256) void gemmout_kernel(
    const float* __restrict__ oacc, const float* __restrict__ lsacc,
    const __bf16* __restrict__ B, float* __restrict__ outF)
{
  constexpr int K = 1024, N = 1024;
  __shared__ __bf16 la[64 * 40];
  __shared__ __bf16 lb[128 * 40];
  const int m0 = blockIdx.y * 64;
  const int n0 = blockIdx.x * 128;
  const int tid = threadIdx.x;
  const int arow = tid >> 2, acol = (tid & 3) * 8;
  const int trow = m0 + arow;
  const __bf16* bp = B + (size_t)(n0 + arow) * K + acol;
  const int w = tid >> 6, lane = tid & 63, lq = lane >> 4, ln = lane & 15;
  const int wm = (w >> 1) * 32, wn = (w & 1) * 64;
  f32x4 acc[2][4] = {};
  for (int k0 = 0; k0 < K; k0 += 32) {
    const int c = k0 + acol;            // 8 cols within one head (8 | 64)
    const int hh = c >> 6, d = c & 63;
    const float* op = oacc + ((size_t)hh * T_ + trow) * D_ + d;
    float4 f0 = *(const float4*)(op);
    float4 f1 = *(const float4*)(op + 4);
    float inv = __builtin_amdgcn_rcpf(lsacc[(size_t)hh * T_ + trow]);
    bf16x8 a0;
    a0[0] = (__bf16)(f0.x * inv); a0[1] = (__bf16)(f0.y * inv);
    a0[2] = (__bf16)(f0.z * inv); a0[3] = (__bf16)(f0.w * inv);
    a0[4] = (__bf16)(f1.x * inv); a0[5] = (__bf16)(f1.y * inv);
    a0[6] = (__bf16)(f1.z * inv); a0[7] = (__bf16)(f1.w * inv);
    bf16x8 b0 = *(const bf16x8*)(bp + k0);
    bf16x8 b1 = *(const bf16x8*)(bp + (size_t)64 * K + k0);
    __syncthreads();
    *(bf16x8*)(la + arow * 40 + acol) = a0;
    *(bf16x8*)(lb + arow * 40 + acol) = b0;
    *(bf16x8*)(lb + (arow + 64) * 40 + acol) = b1;
    __syncthreads();
    bf16x8 af[2], bfr[4];
#pragma unroll
    for (int i = 0; i < 2; ++i)
      af[i] = *(const bf16x8*)(la + (wm + i * 16 + ln) * 40 + lq * 8);
#pragma unroll
    for (int j = 0; j < 4; ++j)
      bfr[j] = *(const bf16x8*)(lb + (wn + j * 16 + ln) * 40 + lq * 8);
#pragma unroll
    for (int i = 0; i < 2; ++i)
#pragma unroll
      for (int j = 0; j < 4; ++j)
        acc[i][j] = MFMA_BF16(af[i], bfr[j], acc[i][j], 0, 0, 0);
  }
#pragma unroll
  for (int i = 0; i < 2; ++i)
#pragma unroll
    for (int j = 0; j < 4; ++j)
#pragma unroll
      for (int r = 0; r < 4; ++r) {
        int row = m0 + wm + i * 16 + lq * 4 + r;
        int col = n0 + wn + j * 16 + ln;
        outF[(size_t)row * N + col] = acc[i][j][r];
      }
}

// ---------------------------------------------------------------------------
// RMSNorm + RoPE + head split, with cumsum FUSED as extra blocks (logf is
// ready: produced by cvtgates two launches earlier). Saves one launch.
// ---------------------------------------------------------------------------
__global__ __launch_bounds__(256) void normrope_kernel(
    const float* __restrict__ qkv, const float* __restrict__ qw,
    const float* __restrict__ kw, __bf16* __restrict__ qh,
    __bf16* __restrict__ kh, __bf16* __restrict__ vh,
    const float* __restrict__ logf, float* __restrict__ csum)
{
  __shared__ float qn[1024];
  __shared__ float kn[256];
  __shared__ float red[16];
  __shared__ float rc[32], rs[32];
  if (blockIdx.x >= T_) {
    // ---- cumsum along T for head h: 3-phase block scan
    const int h = blockIdx.x - T_;
    const int tid = threadIdx.x, lane = tid & 63, w = tid >> 6;
    const float* src = logf + (size_t)h * T_ + tid * 8;
    float4 a = *(const float4*)(src);
    float4 b = *(const float4*)(src + 4);
    float v[8] = {a.x, a.y, a.z, a.w, b.x, b.y, b.z, b.w};
    float t = 0.f;
#pragma unroll
    for (int j = 0; j < 8; ++j) t += v[j];
    float s = t;
#pragma unroll
    for (int d = 1; d < 64; d <<= 1) {
      float u = __shfl_up(s, d);
      if (lane >= d) s += u;
    }
    if (lane == 63) red[w] = s;
    __syncthreads();
    float prefix = 0.f;
#pragma unroll
    for (int ww = 0; ww < 3; ++ww)
      if (ww < w) prefix += red[ww];
    float run = prefix + s - t;
    float* dst = csum + (size_t)h * T_ + tid * 8;
    float4 o0, o1;
    run += v[0]; o0.x = run; run += v[1]; o0.y = run;
    run += v[2]; o0.z = run; run += v[3]; o0.w = run;
    run += v[4]; o1.x = run; run += v[5]; o1.y = run;
    run += v[6]; o1.z = run; run += v[7]; o1.w = run;
    *(float4*)dst = o0;
    *(float4*)(dst + 4) = o1;
    return;
  }
  const int t = blockIdx.x, tid = threadIdx.x;
  if (tid < 32) {
    float fr = (float)t * exp2f((float)tid * -0.41524101186404527f);
    float sn, cs;
    sincosf(fr, &sn, &cs);
    rc[tid] = cs; rs[tid] = sn;
  }
  const float* row = qkv + (size_t)t * 1536;
  float4 q4 = *(const float4*)(row + tid * 4);
  float kvl = row[1024 + tid];
  float vvl = row[1280 + tid];
  float ssq = q4.x * q4.x + q4.y * q4.y + q4.z * q4.z + q4.w * q4.w;
  float ssk = kvl * kvl;
  const int lane = tid & 63, w = tid >> 6;
  for (int m = 32; m; m >>= 1) {
    ssq += __shfl_xor(ssq, m);
    ssk += __shfl_xor(ssk, m);
  }
  if (lane == 0) { red[w] = ssq; red[8 + w] = ssk; }
  __syncthreads();
  float sq = red[0] + red[1] + red[2] + red[3];
  float sk = red[8] + red[9] + red[10] + red[11];
  float rq = rsqrtf(sq * (1.0f / 1024.f) + 1e-6f);
  float rk = rsqrtf(sk * (1.0f / 256.f) + 1e-6f);
  qn[tid * 4 + 0] = q4.x * rq * qw[tid * 4 + 0];
  qn[tid * 4 + 1] = q4.y * rq * qw[tid * 4 + 1];
  qn[tid * 4 + 2] = q4.z * rq * qw[tid * 4 + 2];
  qn[tid * 4 + 3] = q4.w * rq * qw[tid * 4 + 3];
  kn[tid] = kvl * rk * kw[tid];
  __syncthreads();
#pragma unroll
  for (int u = 0; u < 4; ++u) {
    int cidx = tid * 4 + u;
    int hh = cidx >> 6, d = cidx & 63, i = d & 31;
    float cs = rc[i], sn = rs[i];
    float val = (d < 32) ? (qn[cidx] * cs - qn[cidx + 32] * sn)
                         : (qn[cidx] * cs + qn[cidx - 32] * sn);
    qh[(size_t)hh * T_ * D_ + (size_t)t * D_ + d] = (__bf16)val;
  }
  {
    int d = tid & 63, kvhh = tid >> 6, i = d & 31;
    float cs = rc[i], sn = rs[i];
    float kval = (d < 32) ? (kn[tid] * cs - kn[tid + 32] * sn)
                          : (kn[tid] * cs + kn[tid - 32] * sn);
    kh[(size_t)kvhh * T_ * D_ + (size_t)t * D_ + d] = (__bf16)kval;
    vh[(size_t)kvhh * T_ * D_ + (size_t)t * D_ + d] = (__bf16)vvl;
  }
}

// ---------------------------------------------------------------------------
// Transpose V: [KVH][T][D] -> [KVH][D][T]
// ---------------------------------------------------------------------------
__global__ __launch_bounds__(256) void vtrans_kernel(
    const __bf16* __restrict__ vh, __bf16* __restrict__ vt)
{
  const int tb = blockIdx.x, kvh = blockIdx.y;
  __shared__ __bf16 tile[64][72];
  const int tid = threadIdx.x;
  const int r = tid >> 2, cb = (tid & 3) * 16;
  const __bf16* src = vh + (size_t)kvh * T_ * D_ + (size_t)(tb * 64 + r) * D_ + cb;
  bf16x8 v0 = *(const bf16x8*)(src);
  bf16x8 v1 = *(const bf16x8*)(src + 8);
  *(bf16x8*)(&tile[r][cb]) = v0;
  *(bf16x8*)(&tile[r][cb + 8]) = v1;
  __syncthreads();
  bf16x8 o0, o1;
#pragma unroll
  for (int j = 0; j < 8; ++j) o0[j] = tile[cb + j][r];
#pragma unroll
  for (int j = 0; j < 8; ++j) o1[j] = tile[cb + 8 + j][r];
  __bf16* dst = vt + (size_t)kvh * D_ * T_ + (size_t)r * T_ + tb * 64 + cb;
  *(bf16x8*)(dst) = o0;
  *(bf16x8*)(dst + 8) = o1;
}

// v_cvt_pk_bf16_f32: packs cvt(a) into low 16b, cvt(b) into high 16b.
__device__ inline unsigned cvtpk_bf16(float a, float b) {
  unsigned r;
  asm("v_cvt_pk_bf16_f32 %0, %1, %2" : "=v"(r) : "v"(a), "v"(b));
  return r;
}

// ---------------------------------------------------------------------------
// Flash attention v8b = R11's proven v8 (44.9us) with LDS stride 72 -> 76
// (R12's verified conflict-free layout: row r -> bank r*6%32, 16 distinct;
// measured SQ_LDS_BANK_CONFLICT = 0 at this stride vs 2.43M at 72).
// Swapped QK^T (mfma(K,Q)) -> P[k][q=ln]; cvt_pk packed P, 4 ds_write_b64;
// dbuf K/V, single barrier; P aliased in idle K buffer; 1024 uniform blocks.
// ---------------------------------------------------------------------------
__global__ __launch_bounds__(256, 4) void attn_kernel(
    const __bf16* __restrict__ qh, const __bf16* __restrict__ kh,
    const __bf16* __restrict__ vt, const float* __restrict__ csum,
    float* __restrict__ oacc, float* __restrict__ lsacc)
{
  const int bid = blockIdx.x;
  const int wgid = (bid & 7) * (NBLK_ / 8) + (bid >> 3);  // XCD-contiguous
  const int g4 = wgid >> 2, r4 = wgid & 3;
  const int u0 = g4 * 33 + (r4 ? 9 + (r4 - 1) * 8 : 0);
  const int cnt = r4 ? 8 : 9;
  __shared__ __bf16 kbuf[2][64 * LDP_];
  __shared__ __bf16 vbuf[2][64 * LDP_];
  const int tid = threadIdx.x;
  const int w = tid >> 6, lane = tid & 63, lq = lane >> 4, ln = lane & 15;
  const int srow = tid >> 2, scol = (tid & 3) * 16;
  bf16x8 ones;
#pragma unroll
  for (int j = 0; j < 8; ++j) ones[j] = (__bf16)1.0f;

  auto dec = [](int u, int& h, int& ib, int& jt) {
    h = u / UPH_;
    int uh = u - h * UPH_;
    int b = (int)((sqrtf((float)(8 * uh + 1)) - 1.f) * 0.5f);
    if (b * (b + 1) / 2 > uh) --b;
    if ((b + 1) * (b + 2) / 2 <= uh) ++b;
    ib = b; jt = uh - b * (b + 1) / 2;
  };

  int h, ib, jt;
  dec(u0, h, ib, jt);
  int kvh = h >> 2;

  bf16x8 aq0, aq1;
  float ci2;                            // (csum[q] - MSHIFT) * INVLN2, q = ln
  f32x4 o[4] = {};
  f32x4 ls = {0.f, 0.f, 0.f, 0.f};
  auto loadQ = [&](int h_, int i0_) {
    const __bf16* qp = qh + ((size_t)h_ * T_ + i0_ + w * 16 + ln) * D_;
    aq0 = *(const bf16x8*)(qp + lq * 8);
    aq1 = *(const bf16x8*)(qp + 32 + lq * 8);
    ci2 = (csum[(size_t)h_ * T_ + i0_ + w * 16 + ln] - MSHIFT_) * INVLN2_;
#pragma unroll
    for (int dd = 0; dd < 4; ++dd) o[dd] = f32x4{0.f, 0.f, 0.f, 0.f};
    ls = f32x4{0.f, 0.f, 0.f, 0.f};
  };
  loadQ(h, ib * 64);

  auto fetchRegs = [&](int kvh_, int jt_, bf16x8& k0, bf16x8& k1,
                       bf16x8& v0, bf16x8& v1) {
    const __bf16* kb = kh + (size_t)kvh_ * T_ * D_;   // [t][d]
    const __bf16* vb = vt + (size_t)kvh_ * D_ * T_;   // [d][t]
    k0 = *(const bf16x8*)(kb + (size_t)(jt_ * 64 + srow) * D_ + scol);
    k1 = *(const bf16x8*)(kb + (size_t)(jt_ * 64 + srow) * D_ + scol + 8);
    v0 = *(const bf16x8*)(vb + (size_t)srow * T_ + jt_ * 64 + scol);
    v1 = *(const bf16x8*)(vb + (size_t)srow * T_ + jt_ * 64 + scol + 8);
  };
  auto writeStage = [&](int cb, bf16x8 k0, bf16x8 k1, bf16x8 v0, bf16x8 v1) {
    *(bf16x8*)(kbuf[cb] + srow * LDP_ + scol) = k0;
    *(bf16x8*)(kbuf[cb] + srow * LDP_ + scol + 8) = k1;
    *(bf16x8*)(vbuf[cb] + srow * LDP_ + scol) = v0;
    *(bf16x8*)(vbuf[cb] + srow * LDP_ + scol + 8) = v1;
  };

  auto tilebody = [&](int cb, int j0, bool diag) {
    const __bf16* kt = kbuf[cb];
    const __bf16* vtt = vbuf[cb];
    __bf16* pw = kbuf[cb ^ 1] + w * 16 * LDP_; // aliased P scratch (dead K)
    f32x4 cj2[4];
#pragma unroll
    for (int jj = 0; jj < 4; ++jj) {
      float4 c4 = *(const float4*)(csum + (size_t)h * T_ + j0 + jj * 16 + lq * 4);
      cj2[jj] = f32x4{c4.x * INVLN2_, c4.y * INVLN2_,
                      c4.z * INVLN2_, c4.w * INVLN2_};
    }
    f32x4 s[4];
    const f32x4 zf = {0.f, 0.f, 0.f, 0.f};
    __builtin_amdgcn_s_setprio(1);
#pragma unroll
    for (int jj = 0; jj < 4; ++jj) {
      bf16x8 bk0 = *(const bf16x8*)(kt + (jj * 16 + ln) * LDP_ + lq * 8);
      bf16x8 bk1 = *(const bf16x8*)(kt + (jj * 16 + ln) * LDP_ + 32 + lq * 8);
      // SWAPPED: A = K rows, B = Q -> D[k][q=ln]
      s[jj] = MFMA_BF16(bk0, aq0, zf, 0, 0, 0);
      s[jj] = MFMA_BF16(bk1, aq1, s[jj], 0, 0, 0);
    }
    __builtin_amdgcn_s_setprio(0);
    bf16x8 bv0[4], bv1[4];
#pragma unroll
    for (int dd = 0; dd < 4; ++dd) {
      bv0[dd] = *(const bf16x8*)(vtt + (dd * 16 + ln) * LDP_ + lq * 8);
      bv1[dd] = *(const bf16x8*)(vtt + (dd * 16 + ln) * LDP_ + 32 + lq * 8);
    }
    const int qloc = w * 16 + ln;
#pragma unroll
    for (int jj = 0; jj < 4; ++jj) {
      float p[4];
#pragma unroll
      for (int r = 0; r < 4; ++r) {
        float arg = fmaf(s[jj][r], SCALE2_, ci2 - cj2[jj][r]);
        p[r] = exp2f(arg);
        if (diag && (jj * 16 + lq * 4 + r > qloc)) p[r] = 0.f;
      }
      unsigned lo = cvtpk_bf16(p[0], p[1]);
      unsigned hi = cvtpk_bf16(p[2], p[3]);
      uint2 pr; pr.x = lo; pr.y = hi;
      *(uint2*)(pw + ln * LDP_ + jj * 16 + lq * 4) = pr;
    }
    asm volatile("s_waitcnt lgkmcnt(0)" ::: "memory");
    bf16x8 pa0 = *(const bf16x8*)(pw + ln * LDP_ + lq * 8);
    bf16x8 pa1 = *(const bf16x8*)(pw + ln * LDP_ + 32 + lq * 8);
    __builtin_amdgcn_s_setprio(1);
    ls = MFMA_BF16(pa0, ones, ls, 0, 0, 0);
    ls = MFMA_BF16(pa1, ones, ls, 0, 0, 0);
#pragma unroll
    for (int dd = 0; dd < 4; ++dd) {
      o[dd] = MFMA_BF16(pa0, bv0[dd], o[dd], 0, 0, 0);
      o[dd] = MFMA_BF16(pa1, bv1[dd], o[dd], 0, 0, 0);
    }
    __builtin_amdgcn_s_setprio(0);
  };

  auto flush = [&]() {
    const int i0 = ib * 64;
#pragma unroll
    for (int dd = 0; dd < 4; ++dd)
#pragma unroll
      for (int r = 0; r < 4; ++r) {
        int iabs = i0 + w * 16 + lq * 4 + r;
        atomicAdd(oacc + ((size_t)h * T_ + iabs) * D_ + dd * 16 + ln,
                  o[dd][r]);
      }
    if (ln == 0) {
#pragma unroll
      for (int r = 0; r < 4; ++r)
        atomicAdd(lsacc + (size_t)h * T_ + ib * 64 + w * 16 + lq * 4 + r,
                  ls[r]);
    }
  };

  {
    bf16x8 k0, k1, v0, v1;
    fetchRegs(kvh, jt, k0, k1, v0, v1);
    writeStage(0, k0, k1, v0, v1);
  }
  __syncthreads();

  int cur = 0;
#pragma unroll 1
  for (int s = 0; s < cnt; ++s) {
    const bool last = (s == cnt - 1);
    int nh = 0, nib = 0, njt = 0;
    bf16x8 k0, k1, v0, v1;
    if (!last) {
      dec(u0 + s + 1, nh, nib, njt);
      fetchRegs(nh >> 2, njt, k0, k1, v0, v1);   // overlaps tilebody below
    }
    tilebody(cur, jt * 64, jt == ib);
    if (!last) writeStage(cur ^ 1, k0, k1, v0, v1);  // own wave slice only
    const bool rowEnd = last || nib != ib || nh != h;
    if (rowEnd) flush();                             // atomics overlap barrier
    if (!last) {
      __syncthreads();   // single barrier: buf[cur^1] now staged + visible
      if (nh != h || nib != ib) loadQ(nh, nib * 64);
      h = nh; ib = nib; jt = njt; kvh = nh >> 2;
      cur ^= 1;
    }
  }
}

// ---------------------------------------------------------------------------
extern "C" void kernel_launch(void* const* d_in, const int* in_sizes, int n_in,
                              void* d_out, int out_size, void* d_ws, size_t ws_size,
                              hipStream_t stream) {
  const float* x   = (const float*)d_in[0];
  const float* Wq  = (const float*)d_in[1];
  const float* Wk  = (const float*)d_in[2];
  const float* Wv  = (const float*)d_in[3];
  const float* Wo  = (const float*)d_in[4];
  const float* qnw = (const float*)d_in[5];
  const float* knw = (const float*)d_in[6];
  const float* fgw = (const float*)d_in[7];
  const float* fgb = (const float*)d_in[8];
  const float* wl  = (const float*)d_in[9];

  char* ws = (char*)d_ws;
  size_t off = 0;
  float*  qkv  = (float*)(ws + off);  off += (size_t)T_ * 1536 * 4;       // 12.6 MB
  float*  logf = (float*)(ws + off);  off += (size_t)H_ * T_ * 4;
  float*  csum = (float*)(ws + off);  off += (size_t)H_ * T_ * 4;
  __bf16* qh   = (__bf16*)(ws + off); off += (size_t)H_ * T_ * D_ * 2;    // 4 MB
  __bf16* kh   = (__bf16*)(ws + off); off += (size_t)KVH_ * T_ * D_ * 2;
  __bf16* vh   = (__bf16*)(ws + off); off += (size_t)KVH_ * T_ * D_ * 2;
  __bf16* vt   = (__bf16*)(ws + off); off += (size_t)KVH_ * T_ * D_ * 2;
  __bf16* xb   = (__bf16*)(ws + off); off += (size_t)T_ * C_ * 2;         // 4 MB
  __bf16* wqb  = (__bf16*)(ws + off); off += (size_t)C_ * C_ * 2;         // 2 MB
  __bf16* wkb  = (__bf16*)(ws + off); off += (size_t)256 * C_ * 2;
  __bf16* wvb  = (__bf16*)(ws + off); off += (size_t)256 * C_ * 2;
  __bf16* wob  = (__bf16*)(ws + off); off += (size_t)C_ * C_ * 2;         // 2 MB
  // attention partial accumulators -- MUST stay contiguous (zeroed as one
  // 2,129,920-float segment by cvtgates_kernel)
  float*  oacc = (float*)(ws + off);  off += (size_t)H_ * T_ * D_ * 4;    // 8 MB
  float*  lsacc= (float*)(ws + off);  off += (size_t)H_ * T_ * 4;         // 128 KB

  // 0) fp32 -> bf16 conversions + accumulator zero-init + GATES
  cvtgates_kernel<<<3344 + 512, 256, 0, stream>>>(
      x, Wq, Wk, Wv, Wo, wl, xb, wqb, wkb, wvb, wob, oacc, fgw, fgb, logf);
  // 1) QKV projection (bf16): BM=64, 384 blocks
  gemm_bt_kernel<64><<<dim3(12, 32), 256, 0, stream>>>(
      xb, 1024, 1536, wqb, 1024, wkb, 1280, wvb, qkv);
  // 2) RMSNorm + RoPE, with cumsum fused as 16 extra blocks
  normrope_kernel<<<T_ + H_, 256, 0, stream>>>(qkv, qnw, knw, qh, kh, vh,
                                               logf, csum);
  // 3) V transpose
  vtrans_kernel<<<dim3(T_ / 64, KVH_), 256, 0, stream>>>(vh, vt);
  // 4) flash attention v8b (stride-76 conflict-free LDS), 1024 blocks
  attn_kernel<<<NBLK_, 256, 0, stream>>>(qh, kh, vt, csum, oacc, lsacc);
  // 5) output projection with fused finalize -> d_out fp32
  gemmout_kernel<<<dim3(8, 32), 256, 0, stream>>>(
      oacc, lsacc, wob, (float*)d_out);
}

// Round 14
// 191.788 us; speedup vs baseline: 1.2550x; 1.2550x over previous
//
#include <hip/hip_runtime.h>

typedef __bf16 bf16x8 __attribute__((ext_vector_type(8)));
typedef float f32x4 __attribute__((ext_vector_type(4)));

#define MFMA_BF16 __builtin_amdgcn_mfma_f32_16x16x32_bf16

static constexpr int T_ = 2048;
static constexpr int C_ = 1024;
static constexpr int H_ = 16;
static constexpr int KVH_ = 4;
static constexpr int D_ = 64;
static constexpr float INVLN2_ = 1.4426950408889634f;
static constexpr float SCALE2_ = 0.125f * 1.4426950408889634f;
// Fixed softmax shift: scores = qk*SCALE + (ci-cj) with ci-cj<=0 and
// |qk|*SCALE <= 8 (rmsnorm'd) -> row max in [-8, 8]. Shift by 10: exp args
// <= -2 (no overflow); row max term >= exp(-18) (no 0/0). Constant shift =>
// arbitrary j-partials combine by plain summation (no max bookkeeping).
static constexpr float MSHIFT_ = 10.0f;

// Uniform attention work: unit = (h, ib, jt), W = 16*528 = 8448.
// Grid = 1024 blocks exactly (4/CU); groups of 4 blocks cover 33 units
// as 9+8+8+8.
// LDS LESSONS (R12/R13): stride MUST be a multiple of 8 elements (16B) or
// bf16x8 accesses split into b64 (stride 76 doubled attn time; its zero
// conflict count was an artifact of the narrower ops). Stride 72's 2.43M
// conflict cycles ~= 4us spread -- no padding fix exists (bank math:
// uniform 8 lanes per 4-bank group); accepted.
static constexpr int UPH_ = 528;
static constexpr int NBLK_ = 1024;

// ---------------------------------------------------------------------------
// cvt + gates FUSED (R11). Blocks [0,3344): fp32->bf16 + accumulator zero.
// Blocks [3344,3856): gates with wl staged coalesced into LDS + transposed.
// ---------------------------------------------------------------------------
__device__ inline void cvt8(__bf16* dst, const float* src) {
  float4 a = *(const float4*)src;
  float4 b = *(const float4*)(src + 4);
  bf16x8 r;
  r[0] = (__bf16)a.x; r[1] = (__bf16)a.y; r[2] = (__bf16)a.z; r[3] = (__bf16)a.w;
  r[4] = (__bf16)b.x; r[5] = (__bf16)b.y; r[6] = (__bf16)b.z; r[7] = (__bf16)b.w;
  *(bf16x8*)dst = r;
}

__global__ __launch_bounds__(256) void cvtgates_kernel(
    const float* __restrict__ x,  const float* __restrict__ wq,
    const float* __restrict__ wk, const float* __restrict__ wv,
    const float* __restrict__ wo, const float* __restrict__ wl,
    __bf16* __restrict__ xb,  __bf16* __restrict__ wqb,
    __bf16* __restrict__ wkb, __bf16* __restrict__ wvb,
    __bf16* __restrict__ wob, float* __restrict__ zbuf,
    const float* __restrict__ fw, const float* __restrict__ fb,
    float* __restrict__ logf)
{
  __shared__ float wlds[16 * 1024];     // [h][c] transposed wl (64 KB)
  if (blockIdx.x >= 3344) {
    const int t0 = (blockIdx.x - 3344) * 4;
    const int tid = threadIdx.x, w = tid >> 6, lane = tid & 63;
    const float4* wl4 = (const float4*)wl;
#pragma unroll
    for (int j = 0; j < 16; ++j) {
      float4 f = wl4[j * 256 + tid];
      int e = (j * 256 + tid) * 4;
      int c = e >> 4, h0 = e & 15;
      wlds[(h0 + 0) * 1024 + c] = f.x;
      wlds[(h0 + 1) * 1024 + c] = f.y;
      wlds[(h0 + 2) * 1024 + c] = f.z;
      wlds[(h0 + 3) * 1024 + c] = f.w;
    }
    float xv[4][16];
#pragma unroll
    for (int tt = 0; tt < 4; ++tt)
#pragma unroll
      for (int i = 0; i < 16; ++i)
        xv[tt][i] = x[(size_t)(t0 + tt) * C_ + i * 64 + lane];
    __syncthreads();
#pragma unroll
    for (int u = 0; u < 4; ++u) {
      int h = w * 4 + u;
      float wlr[16], fwr[16];
#pragma unroll
      for (int i = 0; i < 16; ++i) {
        wlr[i] = wlds[h * 1024 + i * 64 + lane];
        fwr[i] = fw[(size_t)h * C_ + i * 64 + lane];
      }
#pragma unroll
      for (int tt = 0; tt < 4; ++tt) {
        float s1 = 0.f, s2 = 0.f;
#pragma unroll
        for (int i = 0; i < 16; ++i) {
          s1 += xv[tt][i] * wlr[i];
          s2 += xv[tt][i] * fwr[i];
        }
        for (int m = 32; m; m >>= 1) {
          s1 += __shfl_xor(s1, m);
          s2 += __shfl_xor(s2, m);
        }
        if (lane == 0) {
          float lam = (s1 > 0.f ? s1 : expm1f(s1)) + 1.0f;
          float logit = (s2 + fb[h]) * lam;
          float ls = (logit >= 0.f) ? -log1pf(expf(-logit))
                                    : (logit - log1pf(expf(logit)));
          logf[(size_t)h * T_ + t0 + tt] = ls / (lam + 1e-3f);
        }
      }
    }
    return;
  }
  size_t i8 = ((size_t)blockIdx.x * 256 + threadIdx.x) * 8;
  // segment boundaries (elements): x 2097152 | Wq 1048576 | Wk 262144 |
  // Wv 262144 | Wo 1048576 | zero 2129920
  if (i8 < 2097152)       cvt8(xb  + i8,            x  + i8);
  else if (i8 < 3145728)  cvt8(wqb + (i8-2097152),  wq + (i8-2097152));
  else if (i8 < 3407872)  cvt8(wkb + (i8-3145728),  wk + (i8-3145728));
  else if (i8 < 3670016)  cvt8(wvb + (i8-3407872),  wv + (i8-3407872));
  else if (i8 < 4718592)  cvt8(wob + (i8-3670016),  wo + (i8-3670016));
  else {
    size_t z = i8 - 4718592;
    if (z < 2129920) {
      float4 zz = {0.f, 0.f, 0.f, 0.f};
      *(float4*)(zbuf + z) = zz;
      *(float4*)(zbuf + z + 4) = zz;
    }
  }
}

// ---------------------------------------------------------------------------
// GEMM: out[M,N] = A[M,K] @ B[N,K]^T, all bf16, fp32 out. BM=64, 384 blocks.
// ---------------------------------------------------------------------------
template <int BM>
__global__ __launch_bounds__(256) void gemm_bt_kernel(
    const __bf16* __restrict__ A, int K, int N,
    const __bf16* __restrict__ B0, int e0,
    const __bf16* __restrict__ B1, int e1,
    const __bf16* __restrict__ B2,
    float* __restrict__ outF)
{
  __shared__ __bf16 la[BM * 40];
  __shared__ __bf16 lb[128 * 40];
  const int m0 = blockIdx.y * BM;
  const int n0 = blockIdx.x * 128;
  const __bf16* Bs; int nrel;
  if (n0 < e0)      { Bs = B0; nrel = n0; }
  else if (n0 < e1) { Bs = B1; nrel = n0 - e0; }
  else              { Bs = B2; nrel = n0 - e1; }
  const int tid = threadIdx.x;
  const int arow = tid >> 2, acol = (tid & 3) * 8;
  const __bf16* ap = A  + (size_t)(m0   + arow) * K + acol;
  const __bf16* bp = Bs + (size_t)(nrel + arow) * K + acol;
  const int w = tid >> 6, lane = tid & 63, lq = lane >> 4, ln = lane & 15;
  const int wm = (w >> 1) * (BM / 2), wn = (w & 1) * 64;
  constexpr int FM = BM / 32;
  f32x4 acc[FM][4] = {};
  for (int k0 = 0; k0 < K; k0 += 32) {
    bf16x8 a0 = *(const bf16x8*)(ap + k0);
    bf16x8 a1{};
    if (BM == 128) a1 = *(const bf16x8*)(ap + (size_t)64 * K + k0);
    bf16x8 b0 = *(const bf16x8*)(bp + k0);
    bf16x8 b1 = *(const bf16x8*)(bp + (size_t)64 * K + k0);
    __syncthreads();
    *(bf16x8*)(la + arow * 40 + acol) = a0;
    if (BM == 128) *(bf16x8*)(la + (arow + 64) * 40 + acol) = a1;
    *(bf16x8*)(lb + arow * 40 + acol) = b0;
    *(bf16x8*)(lb + (arow + 64) * 40 + acol) = b1;
    __syncthreads();
    bf16x8 af[FM], bfr[4];
#pragma unroll
    for (int i = 0; i < FM; ++i)
      af[i] = *(const bf16x8*)(la + (wm + i * 16 + ln) * 40 + lq * 8);
#pragma unroll
    for (int j = 0; j < 4; ++j)
      bfr[j] = *(const bf16x8*)(lb + (wn + j * 16 + ln) * 40 + lq * 8);
#pragma unroll
    for (int i = 0; i < FM; ++i)
#pragma unroll
      for (int j = 0; j < 4; ++j)
        acc[i][j] = MFMA_BF16(af[i], bfr[j], acc[i][j], 0, 0, 0);
  }
#pragma unroll
  for (int i = 0; i < FM; ++i)
#pragma unroll
    for (int j = 0; j < 4; ++j)
#pragma unroll
      for (int r = 0; r < 4; ++r) {
        int row = m0 + wm + i * 16 + lq * 4 + r;
        int col = n0 + wn + j * 16 + ln;
        outF[(size_t)row * N + col] = acc[i][j][r];
      }
}

// ---------------------------------------------------------------------------
// Output GEMM with FUSED attention finalize: A[t][c] = oacc[h][t][d]/ls[h][t]
// ---------------------------------------------------------------------------
__global__ __launch_bounds__(256) void gemmout_kernel(
    const float* __restrict__ oacc, const float* __restrict__ lsacc,
    const __bf16* __restrict__ B, float* __restrict__ outF)
{
  constexpr int K = 1024, N = 1024;
  __shared__ __bf16 la[64 * 40];
  __shared__ __bf16 lb[128 * 40];
  const int m0 = blockIdx.y * 64;
  const int n0 = blockIdx.x * 128;
  const int tid = threadIdx.x;
  const int arow = tid >> 2, acol = (tid & 3) * 8;
  const int trow = m0 + arow;
  const __bf16* bp = B + (size_t)(n0 + arow) * K + acol;
  const int w = tid >> 6, lane = tid & 63, lq = lane >> 4, ln = lane & 15;
  const int wm = (w >> 1) * 32, wn = (w & 1) * 64;
  f32x4 acc[2][4] = {};
  for (int k0 = 0; k0 < K; k0 += 32) {
    const int c = k0 + acol;            // 8 cols within one head (8 | 64)
    const int hh = c >> 6, d = c & 63;
    const float* op = oacc + ((size_t)hh * T_ + trow) * D_ + d;
    float4 f0 = *(const float4*)(op);
    float4 f1 = *(const float4*)(op + 4);
    float inv = __builtin_amdgcn_rcpf(lsacc[(size_t)hh * T_ + trow]);
    bf16x8 a0;
    a0[0] = (__bf16)(f0.x * inv); a0[1] = (__bf16)(f0.y * inv);
    a0[2] = (__bf16)(f0.z * inv); a0[3] = (__bf16)(f0.w * inv);
    a0[4] = (__bf16)(f1.x * inv); a0[5] = (__bf16)(f1.y * inv);
    a0[6] = (__bf16)(f1.z * inv); a0[7] = (__bf16)(f1.w * inv);
    bf16x8 b0 = *(const bf16x8*)(bp + k0);
    bf16x8 b1 = *(const bf16x8*)(bp + (size_t)64 * K + k0);
    __syncthreads();
    *(bf16x8*)(la + arow * 40 + acol) = a0;
    *(bf16x8*)(lb + arow * 40 + acol) = b0;
    *(bf16x8*)(lb + (arow + 64) * 40 + acol) = b1;
    __syncthreads();
    bf16x8 af[2], bfr[4];
#pragma unroll
    for (int i = 0; i < 2; ++i)
      af[i] = *(const bf16x8*)(la + (wm + i * 16 + ln) * 40 + lq * 8);
#pragma unroll
    for (int j = 0; j < 4; ++j)
      bfr[j] = *(const bf16x8*)(lb + (wn + j * 16 + ln) * 40 + lq * 8);
#pragma unroll
    for (int i = 0; i < 2; ++i)
#pragma unroll
      for (int j = 0; j < 4; ++j)
        acc[i][j] = MFMA_BF16(af[i], bfr[j], acc[i][j], 0, 0, 0);
  }
#pragma unroll
  for (int i = 0; i < 2; ++i)
#pragma unroll
    for (int j = 0; j < 4; ++j)
#pragma unroll
      for (int r = 0; r < 4; ++r) {
        int row = m0 + wm + i * 16 + lq * 4 + r;
        int col = n0 + wn + j * 16 + ln;
        outF[(size_t)row * N + col] = acc[i][j][r];
      }
}

// ---------------------------------------------------------------------------
// RMSNorm + RoPE + head split, with cumsum FUSED as extra blocks (logf is
// ready: produced by cvtgates two launches earlier). Saves one launch.
// ---------------------------------------------------------------------------
__global__ __launch_bounds__(256) void normrope_kernel(
    const float* __restrict__ qkv, const float* __restrict__ qw,
    const float* __restrict__ kw, __bf16* __restrict__ qh,
    __bf16* __restrict__ kh, __bf16* __restrict__ vh,
    const float* __restrict__ logf, float* __restrict__ csum)
{
  __shared__ float qn[1024];
  __shared__ float kn[256];
  __shared__ float red[16];
  __shared__ float rc[32], rs[32];
  if (blockIdx.x >= T_) {
    // ---- cumsum along T for head h: 3-phase block scan
    const int h = blockIdx.x - T_;
    const int tid = threadIdx.x, lane = tid & 63, w = tid >> 6;
    const float* src = logf + (size_t)h * T_ + tid * 8;
    float4 a = *(const float4*)(src);
    float4 b = *(const float4*)(src + 4);
    float v[8] = {a.x, a.y, a.z, a.w, b.x, b.y, b.z, b.w};
    float t = 0.f;
#pragma unroll
    for (int j = 0; j < 8; ++j) t += v[j];
    float s = t;
#pragma unroll
    for (int d = 1; d < 64; d <<= 1) {
      float u = __shfl_up(s, d);
      if (lane >= d) s += u;
    }
    if (lane == 63) red[w] = s;
    __syncthreads();
    float prefix = 0.f;
#pragma unroll
    for (int ww = 0; ww < 3; ++ww)
      if (ww < w) prefix += red[ww];
    float run = prefix + s - t;
    float* dst = csum + (size_t)h * T_ + tid * 8;
    float4 o0, o1;
    run += v[0]; o0.x = run; run += v[1]; o0.y = run;
    run += v[2]; o0.z = run; run += v[3]; o0.w = run;
    run += v[4]; o1.x = run; run += v[5]; o1.y = run;
    run += v[6]; o1.z = run; run += v[7]; o1.w = run;
    *(float4*)dst = o0;
    *(float4*)(dst + 4) = o1;
    return;
  }
  const int t = blockIdx.x, tid = threadIdx.x;
  if (tid < 32) {
    float fr = (float)t * exp2f((float)tid * -0.41524101186404527f);
    float sn, cs;
    sincosf(fr, &sn, &cs);
    rc[tid] = cs; rs[tid] = sn;
  }
  const float* row = qkv + (size_t)t * 1536;
  float4 q4 = *(const float4*)(row + tid * 4);
  float kvl = row[1024 + tid];
  float vvl = row[1280 + tid];
  float ssq = q4.x * q4.x + q4.y * q4.y + q4.z * q4.z + q4.w * q4.w;
  float ssk = kvl * kvl;
  const int lane = tid & 63, w = tid >> 6;
  for (int m = 32; m; m >>= 1) {
    ssq += __shfl_xor(ssq, m);
    ssk += __shfl_xor(ssk, m);
  }
  if (lane == 0) { red[w] = ssq; red[8 + w] = ssk; }
  __syncthreads();
  float sq = red[0] + red[1] + red[2] + red[3];
  float sk = red[8] + red[9] + red[10] + red[11];
  float rq = rsqrtf(sq * (1.0f / 1024.f) + 1e-6f);
  float rk = rsqrtf(sk * (1.0f / 256.f) + 1e-6f);
  qn[tid * 4 + 0] = q4.x * rq * qw[tid * 4 + 0];
  qn[tid * 4 + 1] = q4.y * rq * qw[tid * 4 + 1];
  qn[tid * 4 + 2] = q4.z * rq * qw[tid * 4 + 2];
  qn[tid * 4 + 3] = q4.w * rq * qw[tid * 4 + 3];
  kn[tid] = kvl * rk * kw[tid];
  __syncthreads();
#pragma unroll
  for (int u = 0; u < 4; ++u) {
    int cidx = tid * 4 + u;
    int hh = cidx >> 6, d = cidx & 63, i = d & 31;
    float cs = rc[i], sn = rs[i];
    float val = (d < 32) ? (qn[cidx] * cs - qn[cidx + 32] * sn)
                         : (qn[cidx] * cs + qn[cidx - 32] * sn);
    qh[(size_t)hh * T_ * D_ + (size_t)t * D_ + d] = (__bf16)val;
  }
  {
    int d = tid & 63, kvhh = tid >> 6, i = d & 31;
    float cs = rc[i], sn = rs[i];
    float kval = (d < 32) ? (kn[tid] * cs - kn[tid + 32] * sn)
                          : (kn[tid] * cs + kn[tid - 32] * sn);
    kh[(size_t)kvhh * T_ * D_ + (size_t)t * D_ + d] = (__bf16)kval;
    vh[(size_t)kvhh * T_ * D_ + (size_t)t * D_ + d] = (__bf16)vvl;
  }
}

// ---------------------------------------------------------------------------
// Transpose V: [KVH][T][D] -> [KVH][D][T]
// ---------------------------------------------------------------------------
__global__ __launch_bounds__(256) void vtrans_kernel(
    const __bf16* __restrict__ vh, __bf16* __restrict__ vt)
{
  const int tb = blockIdx.x, kvh = blockIdx.y;
  __shared__ __bf16 tile[64][72];
  const int tid = threadIdx.x;
  const int r = tid >> 2, cb = (tid & 3) * 16;
  const __bf16* src = vh + (size_t)kvh * T_ * D_ + (size_t)(tb * 64 + r) * D_ + cb;
  bf16x8 v0 = *(const bf16x8*)(src);
  bf16x8 v1 = *(const bf16x8*)(src + 8);
  *(bf16x8*)(&tile[r][cb]) = v0;
  *(bf16x8*)(&tile[r][cb + 8]) = v1;
  __syncthreads();
  bf16x8 o0, o1;
#pragma unroll
  for (int j = 0; j < 8; ++j) o0[j] = tile[cb + j][r];
#pragma unroll
  for (int j = 0; j < 8; ++j) o1[j] = tile[cb + 8 + j][r];
  __bf16* dst = vt + (size_t)kvh * D_ * T_ + (size_t)r * T_ + tb * 64 + cb;
  *(bf16x8*)(dst) = o0;
  *(bf16x8*)(dst + 8) = o1;
}

// v_cvt_pk_bf16_f32: packs cvt(a) into low 16b, cvt(b) into high 16b.
__device__ inline unsigned cvtpk_bf16(float a, float b) {
  unsigned r;
  asm("v_cvt_pk_bf16_f32 %0, %1, %2" : "=v"(r) : "v"(a), "v"(b));
  return r;
}

// ---------------------------------------------------------------------------
// Flash attention v8 = R11's proven kernel (44.9us), stride 72 (16B-aligned;
// R13 lesson: stride must be a multiple of 8 elements or b128 splits).
// Swapped QK^T (mfma(K,Q)) -> P[k][q=ln]; cvt_pk packed P, 4 ds_write_b64;
// dbuf K/V, single barrier; P aliased in idle K buffer; 1024 uniform blocks.
// ---------------------------------------------------------------------------
__global__ __launch_bounds__(256, 4) void attn_kernel(
    const __bf16* __restrict__ qh, const __bf16* __restrict__ kh,
    const __bf16* __restrict__ vt, const float* __restrict__ csum,
    float* __restrict__ oacc, float* __restrict__ lsacc)
{
  const int bid = blockIdx.x;
  const int wgid = (bid & 7) * (NBLK_ / 8) + (bid >> 3);  // XCD-contiguous
  const int g4 = wgid >> 2, r4 = wgid & 3;
  const int u0 = g4 * 33 + (r4 ? 9 + (r4 - 1) * 8 : 0);
  const int cnt = r4 ? 8 : 9;
  __shared__ __bf16 kbuf[2][64 * 72];
  __shared__ __bf16 vbuf[2][64 * 72];
  const int tid = threadIdx.x;
  const int w = tid >> 6, lane = tid & 63, lq = lane >> 4, ln = lane & 15;
  const int srow = tid >> 2, scol = (tid & 3) * 16;
  bf16x8 ones;
#pragma unroll
  for (int j = 0; j < 8; ++j) ones[j] = (__bf16)1.0f;

  auto dec = [](int u, int& h, int& ib, int& jt) {
    h = u / UPH_;
    int uh = u - h * UPH_;
    int b = (int)((sqrtf((float)(8 * uh + 1)) - 1.f) * 0.5f);
    if (b * (b + 1) / 2 > uh) --b;
    if ((b + 1) * (b + 2) / 2 <= uh) ++b;
    ib = b; jt = uh - b * (b + 1) / 2;
  };

  int h, ib, jt;
  dec(u0, h, ib, jt);
  int kvh = h >> 2;

  bf16x8 aq0, aq1;
  float ci2;                            // (csum[q] - MSHIFT) * INVLN2, q = ln
  f32x4 o[4] = {};
  f32x4 ls = {0.f, 0.f, 0.f, 0.f};
  auto loadQ = [&](int h_, int i0_) {
    const __bf16* qp = qh + ((size_t)h_ * T_ + i0_ + w * 16 + ln) * D_;
    aq0 = *(const bf16x8*)(qp + lq * 8);
    aq1 = *(const bf16x8*)(qp + 32 + lq * 8);
    ci2 = (csum[(size_t)h_ * T_ + i0_ + w * 16 + ln] - MSHIFT_) * INVLN2_;
#pragma unroll
    for (int dd = 0; dd < 4; ++dd) o[dd] = f32x4{0.f, 0.f, 0.f, 0.f};
    ls = f32x4{0.f, 0.f, 0.f, 0.f};
  };
  loadQ(h, ib * 64);

  auto fetchRegs = [&](int kvh_, int jt_, bf16x8& k0, bf16x8& k1,
                       bf16x8& v0, bf16x8& v1) {
    const __bf16* kb = kh + (size_t)kvh_ * T_ * D_;   // [t][d]
    const __bf16* vb = vt + (size_t)kvh_ * D_ * T_;   // [d][t]
    k0 = *(const bf16x8*)(kb + (size_t)(jt_ * 64 + srow) * D_ + scol);
    k1 = *(const bf16x8*)(kb + (size_t)(jt_ * 64 + srow) * D_ + scol + 8);
    v0 = *(const bf16x8*)(vb + (size_t)srow * T_ + jt_ * 64 + scol);
    v1 = *(const bf16x8*)(vb + (size_t)srow * T_ + jt_ * 64 + scol + 8);
  };
  auto writeStage = [&](int cb, bf16x8 k0, bf16x8 k1, bf16x8 v0, bf16x8 v1) {
    *(bf16x8*)(kbuf[cb] + srow * 72 + scol) = k0;
    *(bf16x8*)(kbuf[cb] + srow * 72 + scol + 8) = k1;
    *(bf16x8*)(vbuf[cb] + srow * 72 + scol) = v0;
    *(bf16x8*)(vbuf[cb] + srow * 72 + scol + 8) = v1;
  };

  auto tilebody = [&](int cb, int j0, bool diag) {
    const __bf16* kt = kbuf[cb];
    const __bf16* vtt = vbuf[cb];
    __bf16* pw = kbuf[cb ^ 1] + w * 16 * 72;   // aliased P scratch (dead K)
    f32x4 cj2[4];
#pragma unroll
    for (int jj = 0; jj < 4; ++jj) {
      float4 c4 = *(const float4*)(csum + (size_t)h * T_ + j0 + jj * 16 + lq * 4);
      cj2[jj] = f32x4{c4.x * INVLN2_, c4.y * INVLN2_,
                      c4.z * INVLN2_, c4.w * INVLN2_};
    }
    f32x4 s[4];
    const f32x4 zf = {0.f, 0.f, 0.f, 0.f};
    __builtin_amdgcn_s_setprio(1);
#pragma unroll
    for (int jj = 0; jj < 4; ++jj) {
      bf16x8 bk0 = *(const bf16x8*)(kt + (jj * 16 + ln) * 72 + lq * 8);
      bf16x8 bk1 = *(const bf16x8*)(kt + (jj * 16 + ln) * 72 + 32 + lq * 8);
      // SWAPPED: A = K rows, B = Q -> D[k][q=ln]
      s[jj] = MFMA_BF16(bk0, aq0, zf, 0, 0, 0);
      s[jj] = MFMA_BF16(bk1, aq1, s[jj], 0, 0, 0);
    }
    __builtin_amdgcn_s_setprio(0);
    bf16x8 bv0[4], bv1[4];
#pragma unroll
    for (int dd = 0; dd < 4; ++dd) {
      bv0[dd] = *(const bf16x8*)(vtt + (dd * 16 + ln) * 72 + lq * 8);
      bv1[dd] = *(const bf16x8*)(vtt + (dd * 16 + ln) * 72 + 32 + lq * 8);
    }
    const int qloc = w * 16 + ln;
#pragma unroll
    for (int jj = 0; jj < 4; ++jj) {
      float p[4];
#pragma unroll
      for (int r = 0; r < 4; ++r) {
        float arg = fmaf(s[jj][r], SCALE2_, ci2 - cj2[jj][r]);
        p[r] = exp2f(arg);
        if (diag && (jj * 16 + lq * 4 + r > qloc)) p[r] = 0.f;
      }
      unsigned lo = cvtpk_bf16(p[0], p[1]);
      unsigned hi = cvtpk_bf16(p[2], p[3]);
      uint2 pr; pr.x = lo; pr.y = hi;
      *(uint2*)(pw + ln * 72 + jj * 16 + lq * 4) = pr;
    }
    asm volatile("s_waitcnt lgkmcnt(0)" ::: "memory");
    bf16x8 pa0 = *(const bf16x8*)(pw + ln * 72 + lq * 8);
    bf16x8 pa1 = *(const bf16x8*)(pw + ln * 72 + 32 + lq * 8);
    __builtin_amdgcn_s_setprio(1);
    ls = MFMA_BF16(pa0, ones, ls, 0, 0, 0);
    ls = MFMA_BF16(pa1, ones, ls, 0, 0, 0);
#pragma unroll
    for (int dd = 0; dd < 4; ++dd) {
      o[dd] = MFMA_BF16(pa0, bv0[dd], o[dd], 0, 0, 0);
      o[dd] = MFMA_BF16(pa1, bv1[dd], o[dd], 0, 0, 0);
    }
    __builtin_amdgcn_s_setprio(0);
  };

  auto flush = [&]() {
    const int i0 = ib * 64;
#pragma unroll
    for (int dd = 0; dd < 4; ++dd)
#pragma unroll
      for (int r = 0; r < 4; ++r) {
        int iabs = i0 + w * 16 + lq * 4 + r;
        atomicAdd(oacc + ((size_t)h * T_ + iabs) * D_ + dd * 16 + ln,
                  o[dd][r]);
      }
    if (ln == 0) {
#pragma unroll
      for (int r = 0; r < 4; ++r)
        atomicAdd(lsacc + (size_t)h * T_ + ib * 64 + w * 16 + lq * 4 + r,
                  ls[r]);
    }
  };

  {
    bf16x8 k0, k1, v0, v1;
    fetchRegs(kvh, jt, k0, k1, v0, v1);
    writeStage(0, k0, k1, v0, v1);
  }
  __syncthreads();

  int cur = 0;
#pragma unroll 1
  for (int s = 0; s < cnt; ++s) {
    const bool last = (s == cnt - 1);
    int nh = 0, nib = 0, njt = 0;
    bf16x8 k0, k1, v0, v1;
    if (!last) {
      dec(u0 + s + 1, nh, nib, njt);
      fetchRegs(nh >> 2, njt, k0, k1, v0, v1);   // overlaps tilebody below
    }
    tilebody(cur, jt * 64, jt == ib);
    if (!last) writeStage(cur ^ 1, k0, k1, v0, v1);  // own wave slice only
    const bool rowEnd = last || nib != ib || nh != h;
    if (rowEnd) flush();                             // atomics overlap barrier
    if (!last) {
      __syncthreads();   // single barrier: buf[cur^1] now staged + visible
      if (nh != h || nib != ib) loadQ(nh, nib * 64);
      h = nh; ib = nib; jt = njt; kvh = nh >> 2;
      cur ^= 1;
    }
  }
}

// ---------------------------------------------------------------------------
extern "C" void kernel_launch(void* const* d_in, const int* in_sizes, int n_in,
                              void* d_out, int out_size, void* d_ws, size_t ws_size,
                              hipStream_t stream) {
  const float* x   = (const float*)d_in[0];
  const float* Wq  = (const float*)d_in[1];
  const float* Wk  = (const float*)d_in[2];
  const float* Wv  = (const float*)d_in[3];
  const float* Wo  = (const float*)d_in[4];
  const float* qnw = (const float*)d_in[5];
  const float* knw = (const float*)d_in[6];
  const float* fgw = (const float*)d_in[7];
  const float* fgb = (const float*)d_in[8];
  const float* wl  = (const float*)d_in[9];

  char* ws = (char*)d_ws;
  size_t off = 0;
  float*  qkv  = (float*)(ws + off);  off += (size_t)T_ * 1536 * 4;       // 12.6 MB
  float*  logf = (float*)(ws + off);  off += (size_t)H_ * T_ * 4;
  float*  csum = (float*)(ws + off);  off += (size_t)H_ * T_ * 4;
  __bf16* qh   = (__bf16*)(ws + off); off += (size_t)H_ * T_ * D_ * 2;    // 4 MB
  __bf16* kh   = (__bf16*)(ws + off); off += (size_t)KVH_ * T_ * D_ * 2;
  __bf16* vh   = (__bf16*)(ws + off); off += (size_t)KVH_ * T_ * D_ * 2;
  __bf16* vt   = (__bf16*)(ws + off); off += (size_t)KVH_ * T_ * D_ * 2;
  __bf16* xb   = (__bf16*)(ws + off); off += (size_t)T_ * C_ * 2;         // 4 MB
  __bf16* wqb  = (__bf16*)(ws + off); off += (size_t)C_ * C_ * 2;         // 2 MB
  __bf16* wkb  = (__bf16*)(ws + off); off += (size_t)256 * C_ * 2;
  __bf16* wvb  = (__bf16*)(ws + off); off += (size_t)256 * C_ * 2;
  __bf16* wob  = (__bf16*)(ws + off); off += (size_t)C_ * C_ * 2;         // 2 MB
  // attention partial accumulators -- MUST stay contiguous (zeroed as one
  // 2,129,920-float segment by cvtgates_kernel)
  float*  oacc = (float*)(ws + off);  off += (size_t)H_ * T_ * D_ * 4;    // 8 MB
  float*  lsacc= (float*)(ws + off);  off += (size_t)H_ * T_ * 4;         // 128 KB

  // 0) fp32 -> bf16 conversions + accumulator zero-init + GATES
  cvtgates_kernel<<<3344 + 512, 256, 0, stream>>>(
      x, Wq, Wk, Wv, Wo, wl, xb, wqb, wkb, wvb, wob, oacc, fgw, fgb, logf);
  // 1) QKV projection (bf16): BM=64, 384 blocks
  gemm_bt_kernel<64><<<dim3(12, 32), 256, 0, stream>>>(
      xb, 1024, 1536, wqb, 1024, wkb, 1280, wvb, qkv);
  // 2) RMSNorm + RoPE, with cumsum fused as 16 extra blocks
  normrope_kernel<<<T_ + H_, 256, 0, stream>>>(qkv, qnw, knw, qh, kh, vh,
                                               logf, csum);
  // 3) V transpose
  vtrans_kernel<<<dim3(T_ / 64, KVH_), 256, 0, stream>>>(vh, vt);
  // 4) flash attention v8 (stride-72, proven 44.9us), 1024 blocks
  attn_kernel<<<NBLK_, 256, 0, stream>>>(qh, kh, vt, csum, oacc, lsacc);
  // 5) output projection with fused finalize -> d_out fp32
  gemmout_kernel<<<dim3(8, 32), 256, 0, stream>>>(
      oacc, lsacc, wob, (float*)d_out);
}

// Round 15
// 191.376 us; speedup vs baseline: 1.2577x; 1.0022x over previous
//
#include <hip/hip_runtime.h>

typedef __bf16 bf16x8 __attribute__((ext_vector_type(8)));
typedef float f32x4 __attribute__((ext_vector_type(4)));

#define MFMA_BF16 __builtin_amdgcn_mfma_f32_16x16x32_bf16

static constexpr int T_ = 2048;
static constexpr int C_ = 1024;
static constexpr int H_ = 16;
static constexpr int KVH_ = 4;
static constexpr int D_ = 64;
static constexpr float INVLN2_ = 1.4426950408889634f;
static constexpr float SCALE2_ = 0.125f * 1.4426950408889634f;
// Fixed softmax shift: scores = qk*SCALE + (ci-cj) with ci-cj<=0 and
// |qk|*SCALE <= 8 (rmsnorm'd) -> row max in [-8, 8]. Shift by 10: exp args
// <= -2 (no overflow); row max term >= exp(-18) (no 0/0). Constant shift =>
// arbitrary j-partials combine by plain summation (no max bookkeeping).
static constexpr float MSHIFT_ = 10.0f;

// Uniform attention work: unit = (h, ib, jt), W = 16*528 = 8448.
// Grid = 1024 blocks exactly (4/CU); groups of 4 blocks cover 33 units
// as 9+8+8+8.
// LDS LESSONS (R12/R13): stride MUST be a multiple of 8 elements (16B) or
// bf16x8 accesses split into b64 (stride 76 doubled attn time; its zero
// conflict count was an artifact of the narrower ops). Stride 72's 2.43M
// conflict cycles ~= 4us spread -- no padding fix exists; accepted.
static constexpr int UPH_ = 528;
static constexpr int NBLK_ = 1024;

// ---------------------------------------------------------------------------
// cvt + gates FUSED (R11). Blocks [0,3344): fp32->bf16 + accumulator zero.
// Blocks [3344,3856): gates with wl staged coalesced into LDS + transposed.
// ---------------------------------------------------------------------------
__device__ inline void cvt8(__bf16* dst, const float* src) {
  float4 a = *(const float4*)src;
  float4 b = *(const float4*)(src + 4);
  bf16x8 r;
  r[0] = (__bf16)a.x; r[1] = (__bf16)a.y; r[2] = (__bf16)a.z; r[3] = (__bf16)a.w;
  r[4] = (__bf16)b.x; r[5] = (__bf16)b.y; r[6] = (__bf16)b.z; r[7] = (__bf16)b.w;
  *(bf16x8*)dst = r;
}

__global__ __launch_bounds__(256) void cvtgates_kernel(
    const float* __restrict__ x,  const float* __restrict__ wq,
    const float* __restrict__ wk, const float* __restrict__ wv,
    const float* __restrict__ wo, const float* __restrict__ wl,
    __bf16* __restrict__ xb,  __bf16* __restrict__ wqb,
    __bf16* __restrict__ wkb, __bf16* __restrict__ wvb,
    __bf16* __restrict__ wob, float* __restrict__ zbuf,
    const float* __restrict__ fw, const float* __restrict__ fb,
    float* __restrict__ logf)
{
  __shared__ float wlds[16 * 1024];     // [h][c] transposed wl (64 KB)
  if (blockIdx.x >= 3344) {
    const int t0 = (blockIdx.x - 3344) * 4;
    const int tid = threadIdx.x, w = tid >> 6, lane = tid & 63;
    const float4* wl4 = (const float4*)wl;
#pragma unroll
    for (int j = 0; j < 16; ++j) {
      float4 f = wl4[j * 256 + tid];
      int e = (j * 256 + tid) * 4;
      int c = e >> 4, h0 = e & 15;
      wlds[(h0 + 0) * 1024 + c] = f.x;
      wlds[(h0 + 1) * 1024 + c] = f.y;
      wlds[(h0 + 2) * 1024 + c] = f.z;
      wlds[(h0 + 3) * 1024 + c] = f.w;
    }
    float xv[4][16];
#pragma unroll
    for (int tt = 0; tt < 4; ++tt)
#pragma unroll
      for (int i = 0; i < 16; ++i)
        xv[tt][i] = x[(size_t)(t0 + tt) * C_ + i * 64 + lane];
    __syncthreads();
#pragma unroll
    for (int u = 0; u < 4; ++u) {
      int h = w * 4 + u;
      float wlr[16], fwr[16];
#pragma unroll
      for (int i = 0; i < 16; ++i) {
        wlr[i] = wlds[h * 1024 + i * 64 + lane];
        fwr[i] = fw[(size_t)h * C_ + i * 64 + lane];
      }
#pragma unroll
      for (int tt = 0; tt < 4; ++tt) {
        float s1 = 0.f, s2 = 0.f;
#pragma unroll
        for (int i = 0; i < 16; ++i) {
          s1 += xv[tt][i] * wlr[i];
          s2 += xv[tt][i] * fwr[i];
        }
        for (int m = 32; m; m >>= 1) {
          s1 += __shfl_xor(s1, m);
          s2 += __shfl_xor(s2, m);
        }
        if (lane == 0) {
          float lam = (s1 > 0.f ? s1 : expm1f(s1)) + 1.0f;
          float logit = (s2 + fb[h]) * lam;
          float ls = (logit >= 0.f) ? -log1pf(expf(-logit))
                                    : (logit - log1pf(expf(logit)));
          logf[(size_t)h * T_ + t0 + tt] = ls / (lam + 1e-3f);
        }
      }
    }
    return;
  }
  size_t i8 = ((size_t)blockIdx.x * 256 + threadIdx.x) * 8;
  // segment boundaries (elements): x 2097152 | Wq 1048576 | Wk 262144 |
  // Wv 262144 | Wo 1048576 | zero 2129920
  if (i8 < 2097152)       cvt8(xb  + i8,            x  + i8);
  else if (i8 < 3145728)  cvt8(wqb + (i8-2097152),  wq + (i8-2097152));
  else if (i8 < 3407872)  cvt8(wkb + (i8-3145728),  wk + (i8-3145728));
  else if (i8 < 3670016)  cvt8(wvb + (i8-3407872),  wv + (i8-3407872));
  else if (i8 < 4718592)  cvt8(wob + (i8-3670016),  wo + (i8-3670016));
  else {
    size_t z = i8 - 4718592;
    if (z < 2129920) {
      float4 zz = {0.f, 0.f, 0.f, 0.f};
      *(float4*)(zbuf + z) = zz;
      *(float4*)(zbuf + z + 4) = zz;
    }
  }
}

// ---------------------------------------------------------------------------
// GEMM: out[M,N] = A[M,K] @ B[N,K]^T, all bf16, fp32 out. BM=64, 384 blocks.
// ---------------------------------------------------------------------------
template <int BM>
__global__ __launch_bounds__(256) void gemm_bt_kernel(
    const __bf16* __restrict__ A, int K, int N,
    const __bf16* __restrict__ B0, int e0,
    const __bf16* __restrict__ B1, int e1,
    const __bf16* __restrict__ B2,
    float* __restrict__ outF)
{
  __shared__ __bf16 la[BM * 40];
  __shared__ __bf16 lb[128 * 40];
  const int m0 = blockIdx.y * BM;
  const int n0 = blockIdx.x * 128;
  const __bf16* Bs; int nrel;
  if (n0 < e0)      { Bs = B0; nrel = n0; }
  else if (n0 < e1) { Bs = B1; nrel = n0 - e0; }
  else              { Bs = B2; nrel = n0 - e1; }
  const int tid = threadIdx.x;
  const int arow = tid >> 2, acol = (tid & 3) * 8;
  const __bf16* ap = A  + (size_t)(m0   + arow) * K + acol;
  const __bf16* bp = Bs + (size_t)(nrel + arow) * K + acol;
  const int w = tid >> 6, lane = tid & 63, lq = lane >> 4, ln = lane & 15;
  const int wm = (w >> 1) * (BM / 2), wn = (w & 1) * 64;
  constexpr int FM = BM / 32;
  f32x4 acc[FM][4] = {};
  for (int k0 = 0; k0 < K; k0 += 32) {
    bf16x8 a0 = *(const bf16x8*)(ap + k0);
    bf16x8 a1{};
    if (BM == 128) a1 = *(const bf16x8*)(ap + (size_t)64 * K + k0);
    bf16x8 b0 = *(const bf16x8*)(bp + k0);
    bf16x8 b1 = *(const bf16x8*)(bp + (size_t)64 * K + k0);
    __syncthreads();
    *(bf16x8*)(la + arow * 40 + acol) = a0;
    if (BM == 128) *(bf16x8*)(la + (arow + 64) * 40 + acol) = a1;
    *(bf16x8*)(lb + arow * 40 + acol) = b0;
    *(bf16x8*)(lb + (arow + 64) * 40 + acol) = b1;
    __syncthreads();
    bf16x8 af[FM], bfr[4];
#pragma unroll
    for (int i = 0; i < FM; ++i)
      af[i] = *(const bf16x8*)(la + (wm + i * 16 + ln) * 40 + lq * 8);
#pragma unroll
    for (int j = 0; j < 4; ++j)
      bfr[j] = *(const bf16x8*)(lb + (wn + j * 16 + ln) * 40 + lq * 8);
#pragma unroll
    for (int i = 0; i < FM; ++i)
#pragma unroll
      for (int j = 0; j < 4; ++j)
        acc[i][j] = MFMA_BF16(af[i], bfr[j], acc[i][j], 0, 0, 0);
  }
#pragma unroll
  for (int i = 0; i < FM; ++i)
#pragma unroll
    for (int j = 0; j < 4; ++j)
#pragma unroll
      for (int r = 0; r < 4; ++r) {
        int row = m0 + wm + i * 16 + lq * 4 + r;
        int col = n0 + wn + j * 16 + ln;
        outF[(size_t)row * N + col] = acc[i][j][r];
      }
}

// ---------------------------------------------------------------------------
// Output GEMM with FUSED attention finalize: A[t][c] = oacc[h][t][d]/ls[h][t]
// ---------------------------------------------------------------------------
__global__ __launch_bounds__(256) void gemmout_kernel(
    const float* __restrict__ oacc, const float* __restrict__ lsacc,
    const __bf16* __restrict__ B, float* __restrict__ outF)
{
  constexpr int K = 1024, N = 1024;
  __shared__ __bf16 la[64 * 40];
  __shared__ __bf16 lb[128 * 40];
  const int m0 = blockIdx.y * 64;
  const int n0 = blockIdx.x * 128;
  const int tid = threadIdx.x;
  const int arow = tid >> 2, acol = (tid & 3) * 8;
  const int trow = m0 + arow;
  const __bf16* bp = B + (size_t)(n0 + arow) * K + acol;
  const int w = tid >> 6, lane = tid & 63, lq = lane >> 4, ln = lane & 15;
  const int wm = (w >> 1) * 32, wn = (w & 1) * 64;
  f32x4 acc[2][4] = {};
  for (int k0 = 0; k0 < K; k0 += 32) {
    const int c = k0 + acol;            // 8 cols within one head (8 | 64)
    const int hh = c >> 6, d = c & 63;
    const float* op = oacc + ((size_t)hh * T_ + trow) * D_ + d;
    float4 f0 = *(const float4*)(op);
    float4 f1 = *(const float4*)(op + 4);
    float inv = __builtin_amdgcn_rcpf(lsacc[(size_t)hh * T_ + trow]);
    bf16x8 a0;
    a0[0] = (__bf16)(f0.x * inv); a0[1] = (__bf16)(f0.y * inv);
    a0[2] = (__bf16)(f0.z * inv); a0[3] = (__bf16)(f0.w * inv);
    a0[4] = (__bf16)(f1.x * inv); a0[5] = (__bf16)(f1.y * inv);
    a0[6] = (__bf16)(f1.z * inv); a0[7] = (__bf16)(f1.w * inv);
    bf16x8 b0 = *(const bf16x8*)(bp + k0);
    bf16x8 b1 = *(const bf16x8*)(bp + (size_t)64 * K + k0);
    __syncthreads();
    *(bf16x8*)(la + arow * 40 + acol) = a0;
    *(bf16x8*)(lb + arow * 40 + acol) = b0;
    *(bf16x8*)(lb + (arow + 64) * 40 + acol) = b1;
    __syncthreads();
    bf16x8 af[2], bfr[4];
#pragma unroll
    for (int i = 0; i < 2; ++i)
      af[i] = *(const bf16x8*)(la + (wm + i * 16 + ln) * 40 + lq * 8);
#pragma unroll
    for (int j = 0; j < 4; ++j)
      bfr[j] = *(const bf16x8*)(lb + (wn + j * 16 + ln) * 40 + lq * 8);
#pragma unroll
    for (int i = 0; i < 2; ++i)
#pragma unroll
      for (int j = 0; j < 4; ++j)
        acc[i][j] = MFMA_BF16(af[i], bfr[j], acc[i][j], 0, 0, 0);
  }
#pragma unroll
  for (int i = 0; i < 2; ++i)
#pragma unroll
    for (int j = 0; j < 4; ++j)
#pragma unroll
      for (int r = 0; r < 4; ++r) {
        int row = m0 + wm + i * 16 + lq * 4 + r;
        int col = n0 + wn + j * 16 + ln;
        outF[(size_t)row * N + col] = acc[i][j][r];
      }
}

// ---------------------------------------------------------------------------
// RMSNorm + RoPE + head split, cumsum fused as extra blocks, and V written
// DIRECTLY in transposed layout vt[kvh][d][t] (scattered 2B stores; adjacent
// blocks t,t+1 hit adjacent bytes of one 64B line -> L2 write-combines).
// Eliminates the vtrans kernel + the vh buffer (R15).
// ---------------------------------------------------------------------------
__global__ __launch_bounds__(256) void normrope_kernel(
    const float* __restrict__ qkv, const float* __restrict__ qw,
    const float* __restrict__ kw, __bf16* __restrict__ qh,
    __bf16* __restrict__ kh, __bf16* __restrict__ vt,
    const float* __restrict__ logf, float* __restrict__ csum)
{
  __shared__ float qn[1024];
  __shared__ float kn[256];
  __shared__ float red[16];
  __shared__ float rc[32], rs[32];
  if (blockIdx.x >= T_) {
    // ---- cumsum along T for head h: 3-phase block scan
    const int h = blockIdx.x - T_;
    const int tid = threadIdx.x, lane = tid & 63, w = tid >> 6;
    const float* src = logf + (size_t)h * T_ + tid * 8;
    float4 a = *(const float4*)(src);
    float4 b = *(const float4*)(src + 4);
    float v[8] = {a.x, a.y, a.z, a.w, b.x, b.y, b.z, b.w};
    float t = 0.f;
#pragma unroll
    for (int j = 0; j < 8; ++j) t += v[j];
    float s = t;
#pragma unroll
    for (int d = 1; d < 64; d <<= 1) {
      float u = __shfl_up(s, d);
      if (lane >= d) s += u;
    }
    if (lane == 63) red[w] = s;
    __syncthreads();
    float prefix = 0.f;
#pragma unroll
    for (int ww = 0; ww < 3; ++ww)
      if (ww < w) prefix += red[ww];
    float run = prefix + s - t;
    float* dst = csum + (size_t)h * T_ + tid * 8;
    float4 o0, o1;
    run += v[0]; o0.x = run; run += v[1]; o0.y = run;
    run += v[2]; o0.z = run; run += v[3]; o0.w = run;
    run += v[4]; o1.x = run; run += v[5]; o1.y = run;
    run += v[6]; o1.z = run; run += v[7]; o1.w = run;
    *(float4*)dst = o0;
    *(float4*)(dst + 4) = o1;
    return;
  }
  const int t = blockIdx.x, tid = threadIdx.x;
  if (tid < 32) {
    float fr = (float)t * exp2f((float)tid * -0.41524101186404527f);
    float sn, cs;
    sincosf(fr, &sn, &cs);
    rc[tid] = cs; rs[tid] = sn;
  }
  const float* row = qkv + (size_t)t * 1536;
  float4 q4 = *(const float4*)(row + tid * 4);
  float kvl = row[1024 + tid];
  float vvl = row[1280 + tid];
  float ssq = q4.x * q4.x + q4.y * q4.y + q4.z * q4.z + q4.w * q4.w;
  float ssk = kvl * kvl;
  const int lane = tid & 63, w = tid >> 6;
  for (int m = 32; m; m >>= 1) {
    ssq += __shfl_xor(ssq, m);
    ssk += __shfl_xor(ssk, m);
  }
  if (lane == 0) { red[w] = ssq; red[8 + w] = ssk; }
  __syncthreads();
  float sq = red[0] + red[1] + red[2] + red[3];
  float sk = red[8] + red[9] + red[10] + red[11];
  float rq = rsqrtf(sq * (1.0f / 1024.f) + 1e-6f);
  float rk = rsqrtf(sk * (1.0f / 256.f) + 1e-6f);
  qn[tid * 4 + 0] = q4.x * rq * qw[tid * 4 + 0];
  qn[tid * 4 + 1] = q4.y * rq * qw[tid * 4 + 1];
  qn[tid * 4 + 2] = q4.z * rq * qw[tid * 4 + 2];
  qn[tid * 4 + 3] = q4.w * rq * qw[tid * 4 + 3];
  kn[tid] = kvl * rk * kw[tid];
  __syncthreads();
#pragma unroll
  for (int u = 0; u < 4; ++u) {
    int cidx = tid * 4 + u;
    int hh = cidx >> 6, d = cidx & 63, i = d & 31;
    float cs = rc[i], sn = rs[i];
    float val = (d < 32) ? (qn[cidx] * cs - qn[cidx + 32] * sn)
                         : (qn[cidx] * cs + qn[cidx - 32] * sn);
    qh[(size_t)hh * T_ * D_ + (size_t)t * D_ + d] = (__bf16)val;
  }
  {
    int d = tid & 63, kvhh = tid >> 6, i = d & 31;
    float cs = rc[i], sn = rs[i];
    float kval = (d < 32) ? (kn[tid] * cs - kn[tid + 32] * sn)
                          : (kn[tid] * cs + kn[tid - 32] * sn);
    kh[(size_t)kvhh * T_ * D_ + (size_t)t * D_ + d] = (__bf16)kval;
    // V direct transposed store: vt[kvh][d][t] (no rope on V)
    vt[(size_t)kvhh * D_ * T_ + (size_t)d * T_ + t] = (__bf16)vvl;
  }
}

// v_cvt_pk_bf16_f32: packs cvt(a) into low 16b, cvt(b) into high 16b.
__device__ inline unsigned cvtpk_bf16(float a, float b) {
  unsigned r;
  asm("v_cvt_pk_bf16_f32 %0, %1, %2" : "=v"(r) : "v"(a), "v"(b));
  return r;
}

// ---------------------------------------------------------------------------
// Flash attention v8 = R11's proven kernel (44.9us), stride 72 (16B-aligned;
// R13 lesson: stride must be a multiple of 8 elements or b128 splits).
// Swapped QK^T (mfma(K,Q)) -> P[k][q=ln]; cvt_pk packed P, 4 ds_write_b64;
// dbuf K/V, single barrier; P aliased in idle K buffer; 1024 uniform blocks.
// ---------------------------------------------------------------------------
__global__ __launch_bounds__(256, 4) void attn_kernel(
    const __bf16* __restrict__ qh, const __bf16* __restrict__ kh,
    const __bf16* __restrict__ vt, const float* __restrict__ csum,
    float* __restrict__ oacc, float* __restrict__ lsacc)
{
  const int bid = blockIdx.x;
  const int wgid = (bid & 7) * (NBLK_ / 8) + (bid >> 3);  // XCD-contiguous
  const int g4 = wgid >> 2, r4 = wgid & 3;
  const int u0 = g4 * 33 + (r4 ? 9 + (r4 - 1) * 8 : 0);
  const int cnt = r4 ? 8 : 9;
  __shared__ __bf16 kbuf[2][64 * 72];
  __shared__ __bf16 vbuf[2][64 * 72];
  const int tid = threadIdx.x;
  const int w = tid >> 6, lane = tid & 63, lq = lane >> 4, ln = lane & 15;
  const int srow = tid >> 2, scol = (tid & 3) * 16;
  bf16x8 ones;
#pragma unroll
  for (int j = 0; j < 8; ++j) ones[j] = (__bf16)1.0f;

  auto dec = [](int u, int& h, int& ib, int& jt) {
    h = u / UPH_;
    int uh = u - h * UPH_;
    int b = (int)((sqrtf((float)(8 * uh + 1)) - 1.f) * 0.5f);
    if (b * (b + 1) / 2 > uh) --b;
    if ((b + 1) * (b + 2) / 2 <= uh) ++b;
    ib = b; jt = uh - b * (b + 1) / 2;
  };

  int h, ib, jt;
  dec(u0, h, ib, jt);
  int kvh = h >> 2;

  bf16x8 aq0, aq1;
  float ci2;                            // (csum[q] - MSHIFT) * INVLN2, q = ln
  f32x4 o[4] = {};
  f32x4 ls = {0.f, 0.f, 0.f, 0.f};
  auto loadQ = [&](int h_, int i0_) {
    const __bf16* qp = qh + ((size_t)h_ * T_ + i0_ + w * 16 + ln) * D_;
    aq0 = *(const bf16x8*)(qp + lq * 8);
    aq1 = *(const bf16x8*)(qp + 32 + lq * 8);
    ci2 = (csum[(size_t)h_ * T_ + i0_ + w * 16 + ln] - MSHIFT_) * INVLN2_;
#pragma unroll
    for (int dd = 0; dd < 4; ++dd) o[dd] = f32x4{0.f, 0.f, 0.f, 0.f};
    ls = f32x4{0.f, 0.f, 0.f, 0.f};
  };
  loadQ(h, ib * 64);

  auto fetchRegs = [&](int kvh_, int jt_, bf16x8& k0, bf16x8& k1,
                       bf16x8& v0, bf16x8& v1) {
    const __bf16* kb = kh + (size_t)kvh_ * T_ * D_;   // [t][d]
    const __bf16* vb = vt + (size_t)kvh_ * D_ * T_;   // [d][t]
    k0 = *(const bf16x8*)(kb + (size_t)(jt_ * 64 + srow) * D_ + scol);
    k1 = *(const bf16x8*)(kb + (size_t)(jt_ * 64 + srow) * D_ + scol + 8);
    v0 = *(const bf16x8*)(vb + (size_t)srow * T_ + jt_ * 64 + scol);
    v1 = *(const bf16x8*)(vb + (size_t)srow * T_ + jt_ * 64 + scol + 8);
  };
  auto writeStage = [&](int cb, bf16x8 k0, bf16x8 k1, bf16x8 v0, bf16x8 v1) {
    *(bf16x8*)(kbuf[cb] + srow * 72 + scol) = k0;
    *(bf16x8*)(kbuf[cb] + srow * 72 + scol + 8) = k1;
    *(bf16x8*)(vbuf[cb] + srow * 72 + scol) = v0;
    *(bf16x8*)(vbuf[cb] + srow * 72 + scol + 8) = v1;
  };

  auto tilebody = [&](int cb, int j0, bool diag) {
    const __bf16* kt = kbuf[cb];
    const __bf16* vtt = vbuf[cb];
    __bf16* pw = kbuf[cb ^ 1] + w * 16 * 72;   // aliased P scratch (dead K)
    f32x4 cj2[4];
#pragma unroll
    for (int jj = 0; jj < 4; ++jj) {
      float4 c4 = *(const float4*)(csum + (size_t)h * T_ + j0 + jj * 16 + lq * 4);
      cj2[jj] = f32x4{c4.x * INVLN2_, c4.y * INVLN2_,
                      c4.z * INVLN2_, c4.w * INVLN2_};
    }
    f32x4 s[4];
    const f32x4 zf = {0.f, 0.f, 0.f, 0.f};
    __builtin_amdgcn_s_setprio(1);
#pragma unroll
    for (int jj = 0; jj < 4; ++jj) {
      bf16x8 bk0 = *(const bf16x8*)(kt + (jj * 16 + ln) * 72 + lq * 8);
      bf16x8 bk1 = *(const bf16x8*)(kt + (jj * 16 + ln) * 72 + 32 + lq * 8);
      // SWAPPED: A = K rows, B = Q -> D[k][q=ln]
      s[jj] = MFMA_BF16(bk0, aq0, zf, 0, 0, 0);
      s[jj] = MFMA_BF16(bk1, aq1, s[jj], 0, 0, 0);
    }
    __builtin_amdgcn_s_setprio(0);
    bf16x8 bv0[4], bv1[4];
#pragma unroll
    for (int dd = 0; dd < 4; ++dd) {
      bv0[dd] = *(const bf16x8*)(vtt + (dd * 16 + ln) * 72 + lq * 8);
      bv1[dd] = *(const bf16x8*)(vtt + (dd * 16 + ln) * 72 + 32 + lq * 8);
    }
    const int qloc = w * 16 + ln;
#pragma unroll
    for (int jj = 0; jj < 4; ++jj) {
      float p[4];
#pragma unroll
      for (int r = 0; r < 4; ++r) {
        float arg = fmaf(s[jj][r], SCALE2_, ci2 - cj2[jj][r]);
        p[r] = exp2f(arg);
        if (diag && (jj * 16 + lq * 4 + r > qloc)) p[r] = 0.f;
      }
      unsigned lo = cvtpk_bf16(p[0], p[1]);
      unsigned hi = cvtpk_bf16(p[2], p[3]);
      uint2 pr; pr.x = lo; pr.y = hi;
      *(uint2*)(pw + ln * 72 + jj * 16 + lq * 4) = pr;
    }
    asm volatile("s_waitcnt lgkmcnt(0)" ::: "memory");
    bf16x8 pa0 = *(const bf16x8*)(pw + ln * 72 + lq * 8);
    bf16x8 pa1 = *(const bf16x8*)(pw + ln * 72 + 32 + lq * 8);
    __builtin_amdgcn_s_setprio(1);
    ls = MFMA_BF16(pa0, ones, ls, 0, 0, 0);
    ls = MFMA_BF16(pa1, ones, ls, 0, 0, 0);
#pragma unroll
    for (int dd = 0; dd < 4; ++dd) {
      o[dd] = MFMA_BF16(pa0, bv0[dd], o[dd], 0, 0, 0);
      o[dd] = MFMA_BF16(pa1, bv1[dd], o[dd], 0, 0, 0);
    }
    __builtin_amdgcn_s_setprio(0);
  };

  auto flush = [&]() {
    const int i0 = ib * 64;
#pragma unroll
    for (int dd = 0; dd < 4; ++dd)
#pragma unroll
      for (int r = 0; r < 4; ++r) {
        int iabs = i0 + w * 16 + lq * 4 + r;
        atomicAdd(oacc + ((size_t)h * T_ + iabs) * D_ + dd * 16 + ln,
                  o[dd][r]);
      }
    if (ln == 0) {
#pragma unroll
      for (int r = 0; r < 4; ++r)
        atomicAdd(lsacc + (size_t)h * T_ + ib * 64 + w * 16 + lq * 4 + r,
                  ls[r]);
    }
  };

  {
    bf16x8 k0, k1, v0, v1;
    fetchRegs(kvh, jt, k0, k1, v0, v1);
    writeStage(0, k0, k1, v0, v1);
  }
  __syncthreads();

  int cur = 0;
#pragma unroll 1
  for (int s = 0; s < cnt; ++s) {
    const bool last = (s == cnt - 1);
    int nh = 0, nib = 0, njt = 0;
    bf16x8 k0, k1, v0, v1;
    if (!last) {
      dec(u0 + s + 1, nh, nib, njt);
      fetchRegs(nh >> 2, njt, k0, k1, v0, v1);   // overlaps tilebody below
    }
    tilebody(cur, jt * 64, jt == ib);
    if (!last) writeStage(cur ^ 1, k0, k1, v0, v1);  // own wave slice only
    const bool rowEnd = last || nib != ib || nh != h;
    if (rowEnd) flush();                             // atomics overlap barrier
    if (!last) {
      __syncthreads();   // single barrier: buf[cur^1] now staged + visible
      if (nh != h || nib != ib) loadQ(nh, nib * 64);
      h = nh; ib = nib; jt = njt; kvh = nh >> 2;
      cur ^= 1;
    }
  }
}

// ---------------------------------------------------------------------------
extern "C" void kernel_launch(void* const* d_in, const int* in_sizes, int n_in,
                              void* d_out, int out_size, void* d_ws, size_t ws_size,
                              hipStream_t stream) {
  const float* x   = (const float*)d_in[0];
  const float* Wq  = (const float*)d_in[1];
  const float* Wk  = (const float*)d_in[2];
  const float* Wv  = (const float*)d_in[3];
  const float* Wo  = (const float*)d_in[4];
  const float* qnw = (const float*)d_in[5];
  const float* knw = (const float*)d_in[6];
  const float* fgw = (const float*)d_in[7];
  const float* fgb = (const float*)d_in[8];
  const float* wl  = (const float*)d_in[9];

  char* ws = (char*)d_ws;
  size_t off = 0;
  float*  qkv  = (float*)(ws + off);  off += (size_t)T_ * 1536 * 4;       // 12.6 MB
  float*  logf = (float*)(ws + off);  off += (size_t)H_ * T_ * 4;
  float*  csum = (float*)(ws + off);  off += (size_t)H_ * T_ * 4;
  __bf16* qh   = (__bf16*)(ws + off); off += (size_t)H_ * T_ * D_ * 2;    // 4 MB
  __bf16* kh   = (__bf16*)(ws + off); off += (size_t)KVH_ * T_ * D_ * 2;
  __bf16* vt   = (__bf16*)(ws + off); off += (size_t)KVH_ * T_ * D_ * 2;
  __bf16* xb   = (__bf16*)(ws + off); off += (size_t)T_ * C_ * 2;         // 4 MB
  __bf16* wqb  = (__bf16*)(ws + off); off += (size_t)C_ * C_ * 2;         // 2 MB
  __bf16* wkb  = (__bf16*)(ws + off); off += (size_t)256 * C_ * 2;
  __bf16* wvb  = (__bf16*)(ws + off); off += (size_t)256 * C_ * 2;
  __bf16* wob  = (__bf16*)(ws + off); off += (size_t)C_ * C_ * 2;         // 2 MB
  // attention partial accumulators -- MUST stay contiguous (zeroed as one
  // 2,129,920-float segment by cvtgates_kernel)
  float*  oacc = (float*)(ws + off);  off += (size_t)H_ * T_ * D_ * 4;    // 8 MB
  float*  lsacc= (float*)(ws + off);  off += (size_t)H_ * T_ * 4;         // 128 KB

  // 0) fp32 -> bf16 conversions + accumulator zero-init + GATES
  cvtgates_kernel<<<3344 + 512, 256, 0, stream>>>(
      x, Wq, Wk, Wv, Wo, wl, xb, wqb, wkb, wvb, wob, oacc, fgw, fgb, logf);
  // 1) QKV projection (bf16): BM=64, 384 blocks
  gemm_bt_kernel<64><<<dim3(12, 32), 256, 0, stream>>>(
      xb, 1024, 1536, wqb, 1024, wkb, 1280, wvb, qkv);
  // 2) RMSNorm + RoPE (+V direct-transposed store) + cumsum fused
  normrope_kernel<<<T_ + H_, 256, 0, stream>>>(qkv, qnw, knw, qh, kh, vt,
                                               logf, csum);
  // 3) flash attention v8 (stride-72, proven), 1024 blocks
  attn_kernel<<<NBLK_, 256, 0, stream>>>(qh, kh, vt, csum, oacc, lsacc);
  // 4) output projection with fused finalize -> d_out fp32
  gemmout_kernel<<<dim3(8, 32), 256, 0, stream>>>(
      oacc, lsacc, wob, (float*)d_out);
}

// Round 17
// 185.925 us; speedup vs baseline: 1.2946x; 1.0293x over previous
//
#include <hip/hip_runtime.h>

typedef __bf16 bf16x8 __attribute__((ext_vector_type(8)));
typedef float f32x4 __attribute__((ext_vector_type(4)));

#define MFMA_BF16 __builtin_amdgcn_mfma_f32_16x16x32_bf16

static constexpr int T_ = 2048;
static constexpr int C_ = 1024;
static constexpr int H_ = 16;
static constexpr int KVH_ = 4;
static constexpr int D_ = 64;
static constexpr float INVLN2_ = 1.4426950408889634f;
static constexpr float SCALE2_ = 0.125f * 1.4426950408889634f;
// Fixed softmax shift: scores = qk*SCALE + (ci-cj) with ci-cj<=0 and
// |qk|*SCALE <= 8 (rmsnorm'd) -> row max in [-8, 8]. Shift by 10: exp args
// <= -2 (no overflow); row max term >= exp(-18) (no 0/0). Constant shift =>
// arbitrary j-partials combine by plain summation (no max bookkeeping).
static constexpr float MSHIFT_ = 10.0f;

// Uniform attention work: unit = (h, ib, jt), W = 16*528 = 8448.
// Grid = 1024 blocks exactly (4/CU); groups of 4 blocks cover 33 units
// as 9+8+8+8. LDS stride 72 (16B-aligned; R13: non-multiple-of-8 strides
// split b128 ops; R12 conflict counter at 72 is ~4us total, accepted).
static constexpr int UPH_ = 528;
static constexpr int NBLK_ = 1024;

// ---------------------------------------------------------------------------
// cvt + gates FUSED (R11). Blocks [0,3344): fp32->bf16 + accumulator zero.
// Blocks [3344,3856): gates with wl staged coalesced into LDS + transposed.
// ---------------------------------------------------------------------------
__device__ inline void cvt8(__bf16* dst, const float* src) {
  float4 a = *(const float4*)src;
  float4 b = *(const float4*)(src + 4);
  bf16x8 r;
  r[0] = (__bf16)a.x; r[1] = (__bf16)a.y; r[2] = (__bf16)a.z; r[3] = (__bf16)a.w;
  r[4] = (__bf16)b.x; r[5] = (__bf16)b.y; r[6] = (__bf16)b.z; r[7] = (__bf16)b.w;
  *(bf16x8*)dst = r;
}

__global__ __launch_bounds__(256) void cvtgates_kernel(
    const float* __restrict__ x,  const float* __restrict__ wq,
    const float* __restrict__ wk, const float* __restrict__ wv,
    const float* __restrict__ wo, const float* __restrict__ wl,
    __bf16* __restrict__ xb,  __bf16* __restrict__ wqb,
    __bf16* __restrict__ wkb, __bf16* __restrict__ wvb,
    __bf16* __restrict__ wob, float* __restrict__ zbuf,
    const float* __restrict__ fw, const float* __restrict__ fb,
    float* __restrict__ logf)
{
  __shared__ float wlds[16 * 1024];     // [h][c] transposed wl (64 KB)
  if (blockIdx.x >= 3344) {
    const int t0 = (blockIdx.x - 3344) * 4;
    const int tid = threadIdx.x, w = tid >> 6, lane = tid & 63;
    const float4* wl4 = (const float4*)wl;
#pragma unroll
    for (int j = 0; j < 16; ++j) {
      float4 f = wl4[j * 256 + tid];
      int e = (j * 256 + tid) * 4;
      int c = e >> 4, h0 = e & 15;
      wlds[(h0 + 0) * 1024 + c] = f.x;
      wlds[(h0 + 1) * 1024 + c] = f.y;
      wlds[(h0 + 2) * 1024 + c] = f.z;
      wlds[(h0 + 3) * 1024 + c] = f.w;
    }
    float xv[4][16];
#pragma unroll
    for (int tt = 0; tt < 4; ++tt)
#pragma unroll
      for (int i = 0; i < 16; ++i)
        xv[tt][i] = x[(size_t)(t0 + tt) * C_ + i * 64 + lane];
    __syncthreads();
#pragma unroll
    for (int u = 0; u < 4; ++u) {
      int h = w * 4 + u;
      float wlr[16], fwr[16];
#pragma unroll
      for (int i = 0; i < 16; ++i) {
        wlr[i] = wlds[h * 1024 + i * 64 + lane];
        fwr[i] = fw[(size_t)h * C_ + i * 64 + lane];
      }
#pragma unroll
      for (int tt = 0; tt < 4; ++tt) {
        float s1 = 0.f, s2 = 0.f;
#pragma unroll
        for (int i = 0; i < 16; ++i) {
          s1 += xv[tt][i] * wlr[i];
          s2 += xv[tt][i] * fwr[i];
        }
        for (int m = 32; m; m >>= 1) {
          s1 += __shfl_xor(s1, m);
          s2 += __shfl_xor(s2, m);
        }
        if (lane == 0) {
          float lam = (s1 > 0.f ? s1 : expm1f(s1)) + 1.0f;
          float logit = (s2 + fb[h]) * lam;
          float ls = (logit >= 0.f) ? -log1pf(expf(-logit))
                                    : (logit - log1pf(expf(logit)));
          logf[(size_t)h * T_ + t0 + tt] = ls / (lam + 1e-3f);
        }
      }
    }
    return;
  }
  size_t i8 = ((size_t)blockIdx.x * 256 + threadIdx.x) * 8;
  // segment boundaries (elements): x 2097152 | Wq 1048576 | Wk 262144 |
  // Wv 262144 | Wo 1048576 | zero 2129920
  if (i8 < 2097152)       cvt8(xb  + i8,            x  + i8);
  else if (i8 < 3145728)  cvt8(wqb + (i8-2097152),  wq + (i8-2097152));
  else if (i8 < 3407872)  cvt8(wkb + (i8-3145728),  wk + (i8-3145728));
  else if (i8 < 3670016)  cvt8(wvb + (i8-3407872),  wv + (i8-3407872));
  else if (i8 < 4718592)  cvt8(wob + (i8-3670016),  wo + (i8-3670016));
  else {
    size_t z = i8 - 4718592;
    if (z < 2129920) {
      float4 zz = {0.f, 0.f, 0.f, 0.f};
      *(float4*)(zbuf + z) = zz;
      *(float4*)(zbuf + z + 4) = zz;
    }
  }
}

// ---------------------------------------------------------------------------
// GEMM v2: out[M,N] = A[M,K] @ B[N,K]^T, BM=BN=BK=64, 4 waves each 16x64.
// R16: exact-fill grids (QKV: 768 = 3.0/CU, kills the 1.5/CU 2-generation
// imbalance of the old 384-block BN=128 version); BK=64 halves barriers.
// ---------------------------------------------------------------------------
__global__ __launch_bounds__(256) void gemm64_kernel(
    const __bf16* __restrict__ A, int K, int N,
    const __bf16* __restrict__ B0, int e0,
    const __bf16* __restrict__ B1, int e1,
    const __bf16* __restrict__ B2,
    float* __restrict__ outF)
{
  __shared__ __bf16 la[64 * 72];
  __shared__ __bf16 lb[64 * 72];
  const int m0 = blockIdx.y * 64;
  const int n0 = blockIdx.x * 64;
  const __bf16* Bs; int nrel;
  if (n0 < e0)      { Bs = B0; nrel = n0; }
  else if (n0 < e1) { Bs = B1; nrel = n0 - e0; }
  else              { Bs = B2; nrel = n0 - e1; }
  const int tid = threadIdx.x;
  const int srow = tid >> 2, scol = (tid & 3) * 16;
  const __bf16* ap = A  + (size_t)(m0   + srow) * K + scol;
  const __bf16* bp = Bs + (size_t)(nrel + srow) * K + scol;
  const int w = tid >> 6, lane = tid & 63, lq = lane >> 4, ln = lane & 15;
  const int wm = w * 16;
  f32x4 acc[4] = {};
  for (int k0 = 0; k0 < K; k0 += 64) {
    bf16x8 a0 = *(const bf16x8*)(ap + k0);
    bf16x8 a1 = *(const bf16x8*)(ap + k0 + 8);
    bf16x8 b0 = *(const bf16x8*)(bp + k0);
    bf16x8 b1 = *(const bf16x8*)(bp + k0 + 8);
    __syncthreads();
    *(bf16x8*)(la + srow * 72 + scol) = a0;
    *(bf16x8*)(la + srow * 72 + scol + 8) = a1;
    *(bf16x8*)(lb + srow * 72 + scol) = b0;
    *(bf16x8*)(lb + srow * 72 + scol + 8) = b1;
    __syncthreads();
#pragma unroll
    for (int kk = 0; kk < 2; ++kk) {
      bf16x8 af = *(const bf16x8*)(la + (wm + ln) * 72 + kk * 32 + lq * 8);
#pragma unroll
      for (int j = 0; j < 4; ++j) {
        bf16x8 bfr = *(const bf16x8*)(lb + (j * 16 + ln) * 72 + kk * 32 + lq * 8);
        acc[j] = MFMA_BF16(af, bfr, acc[j], 0, 0, 0);
      }
    }
  }
#pragma unroll
  for (int j = 0; j < 4; ++j)
#pragma unroll
    for (int r = 0; r < 4; ++r) {
      int row = m0 + wm + lq * 4 + r;
      int col = n0 + j * 16 + ln;
      outF[(size_t)row * N + col] = acc[j][r];
    }
}

// ---------------------------------------------------------------------------
// Output GEMM v2 with FUSED attention finalize: BM=BN=BK=64, grid (16,32) =
// 512 blocks = 2.0/CU (old 256 = 1/CU had only 4 waves/CU of latency hiding).
// A[t][c] = oacc[h][t][d]/ls[h][t]; 16-col slices stay within one head
// (k0 % 64 == 0, scol in {0,16,32,48}).
// ---------------------------------------------------------------------------
__global__ __launch_bounds__(256) void gemmout_kernel(
    const float* __restrict__ oacc, const float* __restrict__ lsacc,
    const __bf16* __restrict__ B, float* __restrict__ outF)
{
  constexpr int K = 1024, N = 1024;
  __shared__ __bf16 la[64 * 72];
  __shared__ __bf16 lb[64 * 72];
  const int m0 = blockIdx.y * 64;
  const int n0 = blockIdx.x * 64;
  const int tid = threadIdx.x;
  const int srow = tid >> 2, scol = (tid & 3) * 16;
  const int trow = m0 + srow;
  const __bf16* bp = B + (size_t)(n0 + srow) * K + scol;
  const int w = tid >> 6, lane = tid & 63, lq = lane >> 4, ln = lane & 15;
  const int wm = w * 16;
  f32x4 acc[4] = {};
  for (int k0 = 0; k0 < K; k0 += 64) {
    const int c = k0 + scol;            // 16 cols within one head (16 | 64)
    const int hh = c >> 6, d = c & 63;
    const float* op = oacc + ((size_t)hh * T_ + trow) * D_ + d;
    float4 f0 = *(const float4*)(op);
    float4 f1 = *(const float4*)(op + 4);
    float4 f2 = *(const float4*)(op + 8);
    float4 f3 = *(const float4*)(op + 12);
    float inv = __builtin_amdgcn_rcpf(lsacc[(size_t)hh * T_ + trow]);
    bf16x8 a0, a1;
    a0[0] = (__bf16)(f0.x * inv); a0[1] = (__bf16)(f0.y * inv);
    a0[2] = (__bf16)(f0.z * inv); a0[3] = (__bf16)(f0.w * inv);
    a0[4] = (__bf16)(f1.x * inv); a0[5] = (__bf16)(f1.y * inv);
    a0[6] = (__bf16)(f1.z * inv); a0[7] = (__bf16)(f1.w * inv);
    a1[0] = (__bf16)(f2.x * inv); a1[1] = (__bf16)(f2.y * inv);
    a1[2] = (__bf16)(f2.z * inv); a1[3] = (__bf16)(f2.w * inv);
    a1[4] = (__bf16)(f3.x * inv); a1[5] = (__bf16)(f3.y * inv);
    a1[6] = (__bf16)(f3.z * inv); a1[7] = (__bf16)(f3.w * inv);
    bf16x8 b0 = *(const bf16x8*)(bp + k0);
    bf16x8 b1 = *(const bf16x8*)(bp + k0 + 8);
    __syncthreads();
    *(bf16x8*)(la + srow * 72 + scol) = a0;
    *(bf16x8*)(la + srow * 72 + scol + 8) = a1;
    *(bf16x8*)(lb + srow * 72 + scol) = b0;
    *(bf16x8*)(lb + srow * 72 + scol + 8) = b1;
    __syncthreads();
#pragma unroll
    for (int kk = 0; kk < 2; ++kk) {
      bf16x8 af = *(const bf16x8*)(la + (wm + ln) * 72 + kk * 32 + lq * 8);
#pragma unroll
      for (int j = 0; j < 4; ++j) {
        bf16x8 bfr = *(const bf16x8*)(lb + (j * 16 + ln) * 72 + kk * 32 + lq * 8);
        acc[j] = MFMA_BF16(af, bfr, acc[j], 0, 0, 0);
      }
    }
  }
#pragma unroll
  for (int j = 0; j < 4; ++j)
#pragma unroll
    for (int r = 0; r < 4; ++r) {
      int row = m0 + wm + lq * 4 + r;
      int col = n0 + j * 16 + ln;
      outF[(size_t)row * N + col] = acc[j][r];
    }
}

// ---------------------------------------------------------------------------
// RMSNorm + RoPE + head split, cumsum fused as extra blocks, V written
// directly transposed vt[kvh][d][t] (R15; adjacent blocks write adjacent
// bytes of one 64B line -> L2 write-combines).
// ---------------------------------------------------------------------------
__global__ __launch_bounds__(256) void normrope_kernel(
    const float* __restrict__ qkv, const float* __restrict__ qw,
    const float* __restrict__ kw, __bf16* __restrict__ qh,
    __bf16* __restrict__ kh, __bf16* __restrict__ vt,
    const float* __restrict__ logf, float* __restrict__ csum)
{
  __shared__ float qn[1024];
  __shared__ float kn[256];
  __shared__ float red[16];
  __shared__ float rc[32], rs[32];
  if (blockIdx.x >= T_) {
    // ---- cumsum along T for head h: 3-phase block scan
    const int h = blockIdx.x - T_;
    const int tid = threadIdx.x, lane = tid & 63, w = tid >> 6;
    const float* src = logf + (size_t)h * T_ + tid * 8;
    float4 a = *(const float4*)(src);
    float4 b = *(const float4*)(src + 4);
    float v[8] = {a.x, a.y, a.z, a.w, b.x, b.y, b.z, b.w};
    float t = 0.f;
#pragma unroll
    for (int j = 0; j < 8; ++j) t += v[j];
    float s = t;
#pragma unroll
    for (int d = 1; d < 64; d <<= 1) {
      float u = __shfl_up(s, d);
      if (lane >= d) s += u;
    }
    if (lane == 63) red[w] = s;
    __syncthreads();
    float prefix = 0.f;
#pragma unroll
    for (int ww = 0; ww < 3; ++ww)
      if (ww < w) prefix += red[ww];
    float run = prefix + s - t;
    float* dst = csum + (size_t)h * T_ + tid * 8;
    float4 o0, o1;
    run += v[0]; o0.x = run; run += v[1]; o0.y = run;
    run += v[2]; o0.z = run; run += v[3]; o0.w = run;
    run += v[4]; o1.x = run; run += v[5]; o1.y = run;
    run += v[6]; o1.z = run; run += v[7]; o1.w = run;
    *(float4*)dst = o0;
    *(float4*)(dst + 4) = o1;
    return;
  }
  const int t = blockIdx.x, tid = threadIdx.x;
  if (tid < 32) {
    float fr = (float)t * exp2f((float)tid * -0.41524101186404527f);
    float sn, cs;
    sincosf(fr, &sn, &cs);
    rc[tid] = cs; rs[tid] = sn;
  }
  const float* row = qkv + (size_t)t * 1536;
  float4 q4 = *(const float4*)(row + tid * 4);
  float kvl = row[1024 + tid];
  float vvl = row[1280 + tid];
  float ssq = q4.x * q4.x + q4.y * q4.y + q4.z * q4.z + q4.w * q4.w;
  float ssk = kvl * kvl;
  const int lane = tid & 63, w = tid >> 6;
  for (int m = 32; m; m >>= 1) {
    ssq += __shfl_xor(ssq, m);
    ssk += __shfl_xor(ssk, m);
  }
  if (lane == 0) { red[w] = ssq; red[8 + w] = ssk; }
  __syncthreads();
  float sq = red[0] + red[1] + red[2] + red[3];
  float sk = red[8] + red[9] + red[10] + red[11];
  float rq = rsqrtf(sq * (1.0f / 1024.f) + 1e-6f);
  float rk = rsqrtf(sk * (1.0f / 256.f) + 1e-6f);
  qn[tid * 4 + 0] = q4.x * rq * qw[tid * 4 + 0];
  qn[tid * 4 + 1] = q4.y * rq * qw[tid * 4 + 1];
  qn[tid * 4 + 2] = q4.z * rq * qw[tid * 4 + 2];
  qn[tid * 4 + 3] = q4.w * rq * qw[tid * 4 + 3];
  kn[tid] = kvl * rk * kw[tid];
  __syncthreads();
#pragma unroll
  for (int u = 0; u < 4; ++u) {
    int cidx = tid * 4 + u;
    int hh = cidx >> 6, d = cidx & 63, i = d & 31;
    float cs = rc[i], sn = rs[i];
    float val = (d < 32) ? (qn[cidx] * cs - qn[cidx + 32] * sn)
                         : (qn[cidx] * cs + qn[cidx - 32] * sn);
    qh[(size_t)hh * T_ * D_ + (size_t)t * D_ + d] = (__bf16)val;
  }
  {
    int d = tid & 63, kvhh = tid >> 6, i = d & 31;
    float cs = rc[i], sn = rs[i];
    float kval = (d < 32) ? (kn[tid] * cs - kn[tid + 32] * sn)
                          : (kn[tid] * cs + kn[tid - 32] * sn);
    kh[(size_t)kvhh * T_ * D_ + (size_t)t * D_ + d] = (__bf16)kval;
    // V direct transposed store: vt[kvh][d][t] (no rope on V)
    vt[(size_t)kvhh * D_ * T_ + (size_t)d * T_ + t] = (__bf16)vvl;
  }
}

// v_cvt_pk_bf16_f32: packs cvt(a) into low 16b, cvt(b) into high 16b.
__device__ inline unsigned cvtpk_bf16(float a, float b) {
  unsigned r;
  asm("v_cvt_pk_bf16_f32 %0, %1, %2" : "=v"(r) : "v"(a), "v"(b));
  return r;
}

// ---------------------------------------------------------------------------
// Flash attention v8 (R11, proven 44.9us): swapped QK^T (mfma(K,Q)) ->
// P[k][q=ln]; cvt_pk packed P, 4 ds_write_b64; dbuf K/V, single barrier;
// P aliased in idle K buffer; 1024 uniform blocks; stride-72 LDS.
// ---------------------------------------------------------------------------
__global__ __launch_bounds__(256, 4) void attn_kernel(
    const __bf16* __restrict__ qh, const __bf16* __restrict__ kh,
    const __bf16* __restrict__ vt, const float* __restrict__ csum,
    float* __restrict__ oacc, float* __restrict__ lsacc)
{
  const int bid = blockIdx.x;
  const int wgid = (bid & 7) * (NBLK_ / 8) + (bid >> 3);  // XCD-contiguous
  const int g4 = wgid >> 2, r4 = wgid & 3;
  const int u0 = g4 * 33 + (r4 ? 9 + (r4 - 1) * 8 : 0);
  const int cnt = r4 ? 8 : 9;
  __shared__ __bf16 kbuf[2][64 * 72];
  __shared__ __bf16 vbuf[2][64 * 72];
  const int tid = threadIdx.x;
  const int w = tid >> 6, lane = tid & 63, lq = lane >> 4, ln = lane & 15;
  const int srow = tid >> 2, scol = (tid & 3) * 16;
  bf16x8 ones;
#pragma unroll
  for (int j = 0; j < 8; ++j) ones[j] = (__bf16)1.0f;

  auto dec = [](int u, int& h, int& ib, int& jt) {
    h = u / UPH_;
    int uh = u - h * UPH_;
    int b = (int)((sqrtf((float)(8 * uh + 1)) - 1.f) * 0.5f);
    if (b * (b + 1) / 2 > uh) --b;
    if ((b + 1) * (b + 2) / 2 <= uh) ++b;
    ib = b; jt = uh - b * (b + 1) / 2;
  };

  int h, ib, jt;
  dec(u0, h, ib, jt);
  int kvh = h >> 2;

  bf16x8 aq0, aq1;
  float ci2;                            // (csum[q] - MSHIFT) * INVLN2, q = ln
  f32x4 o[4] = {};
  f32x4 ls = {0.f, 0.f, 0.f, 0.f};
  auto loadQ = [&](int h_, int i0_) {
    const __bf16* qp = qh + ((size_t)h_ * T_ + i0_ + w * 16 + ln) * D_;
    aq0 = *(const bf16x8*)(qp + lq * 8);
    aq1 = *(const bf16x8*)(qp + 32 + lq * 8);
    ci2 = (csum[(size_t)h_ * T_ + i0_ + w * 16 + ln] - MSHIFT_) * INVLN2_;
#pragma unroll
    for (int dd = 0; dd < 4; ++dd) o[dd] = f32x4{0.f, 0.f, 0.f, 0.f};
    ls = f32x4{0.f, 0.f, 0.f, 0.f};
  };
  loadQ(h, ib * 64);

  auto fetchRegs = [&](int kvh_, int jt_, bf16x8& k0, bf16x8& k1,
                       bf16x8& v0, bf16x8& v1) {
    const __bf16* kb = kh + (size_t)kvh_ * T_ * D_;   // [t][d]
    const __bf16* vb = vt + (size_t)kvh_ * D_ * T_;   // [d][t]
    k0 = *(const bf16x8*)(kb + (size_t)(jt_ * 64 + srow) * D_ + scol);
    k1 = *(const bf16x8*)(kb + (size_t)(jt_ * 64 + srow) * D_ + scol + 8);
    v0 = *(const bf16x8*)(vb + (size_t)srow * T_ + jt_ * 64 + scol);
    v1 = *(const bf16x8*)(vb + (size_t)srow * T_ + jt_ * 64 + scol + 8);
  };
  auto writeStage = [&](int cb, bf16x8 k0, bf16x8 k1, bf16x8 v0, bf16x8 v1) {
    *(bf16x8*)(kbuf[cb] + srow * 72 + scol) = k0;
    *(bf16x8*)(kbuf[cb] + srow * 72 + scol + 8) = k1;
    *(bf16x8*)(vbuf[cb] + srow * 72 + scol) = v0;
    *(bf16x8*)(vbuf[cb] + srow * 72 + scol + 8) = v1;
  };

  auto tilebody = [&](int cb, int j0, bool diag) {
    const __bf16* kt = kbuf[cb];
    const __bf16* vtt = vbuf[cb];
    __bf16* pw = kbuf[cb ^ 1] + w * 16 * 72;   // aliased P scratch (dead K)
    f32x4 cj2[4];
#pragma unroll
    for (int jj = 0; jj < 4; ++jj) {
      float4 c4 = *(const float4*)(csum + (size_t)h * T_ + j0 + jj * 16 + lq * 4);
      cj2[jj] = f32x4{c4.x * INVLN2_, c4.y * INVLN2_,
                      c4.z * INVLN2_, c4.w * INVLN2_};
    }
    f32x4 s[4];
    const f32x4 zf = {0.f, 0.f, 0.f, 0.f};
    __builtin_amdgcn_s_setprio(1);
#pragma unroll
    for (int jj = 0; jj < 4; ++jj) {
      bf16x8 bk0 = *(const bf16x8*)(kt + (jj * 16 + ln) * 72 + lq * 8);
      bf16x8 bk1 = *(const bf16x8*)(kt + (jj * 16 + ln) * 72 + 32 + lq * 8);
      // SWAPPED: A = K rows, B = Q -> D[k][q=ln]
      s[jj] = MFMA_BF16(bk0, aq0, zf, 0, 0, 0);
      s[jj] = MFMA_BF16(bk1, aq1, s[jj], 0, 0, 0);
    }
    __builtin_amdgcn_s_setprio(0);
    bf16x8 bv0[4], bv1[4];
#pragma unroll
    for (int dd = 0; dd < 4; ++dd) {
      bv0[dd] = *(const bf16x8*)(vtt + (dd * 16 + ln) * 72 + lq * 8);
      bv1[dd] = *(const bf16x8*)(vtt + (dd * 16 + ln) * 72 + 32 + lq * 8);
    }
    const int qloc = w * 16 + ln;
#pragma unroll
    for (int jj = 0; jj < 4; ++jj) {
      float p[4];
#pragma unroll
      for (int r = 0; r < 4; ++r) {
        float arg = fmaf(s[jj][r], SCALE2_, ci2 - cj2[jj][r]);
        p[r] = exp2f(arg);
        if (diag && (jj * 16 + lq * 4 + r > qloc)) p[r] = 0.f;
      }
      unsigned lo = cvtpk_bf16(p[0], p[1]);
      unsigned hi = cvtpk_bf16(p[2], p[3]);
      uint2 pr; pr.x = lo; pr.y = hi;
      *(uint2*)(pw + ln * 72 + jj * 16 + lq * 4) = pr;
    }
    asm volatile("s_waitcnt lgkmcnt(0)" ::: "memory");
    bf16x8 pa0 = *(const bf16x8*)(pw + ln * 72 + lq * 8);
    bf16x8 pa1 = *(const bf16x8*)(pw + ln * 72 + 32 + lq * 8);
    __builtin_amdgcn_s_setprio(1);
    ls = MFMA_BF16(pa0, ones, ls, 0, 0, 0);
    ls = MFMA_BF16(pa1, ones, ls, 0, 0, 0);
#pragma unroll
    for (int dd = 0; dd < 4; ++dd) {
      o[dd] = MFMA_BF16(pa0, bv0[dd], o[dd], 0, 0, 0);
      o[dd] = MFMA_BF16(pa1, bv1[dd], o[dd], 0, 0, 0);
    }
    __builtin_amdgcn_s_setprio(0);
  };

  auto flush = [&]() {
    const int i0 = ib * 64;
#pragma unroll
    for (int dd = 0; dd < 4; ++dd)
#pragma unroll
      for (int r = 0; r < 4; ++r) {
        int iabs = i0 + w * 16 + lq * 4 + r;
        atomicAdd(oacc + ((size_t)h * T_ + iabs) * D_ + dd * 16 + ln,
                  o[dd][r]);
      }
    if (ln == 0) {
#pragma unroll
      for (int r = 0; r < 4; ++r)
        atomicAdd(lsacc + (size_t)h * T_ + ib * 64 + w * 16 + lq * 4 + r,
                  ls[r]);
    }
  };

  {
    bf16x8 k0, k1, v0, v1;
    fetchRegs(kvh, jt, k0, k1, v0, v1);
    writeStage(0, k0, k1, v0, v1);
  }
  __syncthreads();

  int cur = 0;
#pragma unroll 1
  for (int s = 0; s < cnt; ++s) {
    const bool last = (s == cnt - 1);
    int nh = 0, nib = 0, njt = 0;
    bf16x8 k0, k1, v0, v1;
    if (!last) {
      dec(u0 + s + 1, nh, nib, njt);
      fetchRegs(nh >> 2, njt, k0, k1, v0, v1);   // overlaps tilebody below
    }
    tilebody(cur, jt * 64, jt == ib);
    if (!last) writeStage(cur ^ 1, k0, k1, v0, v1);  // own wave slice only
    const bool rowEnd = last || nib != ib || nh != h;
    if (rowEnd) flush();                             // atomics overlap barrier
    if (!last) {
      __syncthreads();   // single barrier: buf[cur^1] now staged + visible
      if (nh != h || nib != ib) loadQ(nh, nib * 64);
      h = nh; ib = nib; jt = njt; kvh = nh >> 2;
      cur ^= 1;
    }
  }
}

// ---------------------------------------------------------------------------
extern "C" void kernel_launch(void* const* d_in, const int* in_sizes, int n_in,
                              void* d_out, int out_size, void* d_ws, size_t ws_size,
                              hipStream_t stream) {
  const float* x   = (const float*)d_in[0];
  const float* Wq  = (const float*)d_in[1];
  const float* Wk  = (const float*)d_in[2];
  const float* Wv  = (const float*)d_in[3];
  const float* Wo  = (const float*)d_in[4];
  const float* qnw = (const float*)d_in[5];
  const float* knw = (const float*)d_in[6];
  const float* fgw = (const float*)d_in[7];
  const float* fgb = (const float*)d_in[8];
  const float* wl  = (const float*)d_in[9];

  char* ws = (char*)d_ws;
  size_t off = 0;
  float*  qkv  = (float*)(ws + off);  off += (size_t)T_ * 1536 * 4;       // 12.6 MB
  float*  logf = (float*)(ws + off);  off += (size_t)H_ * T_ * 4;
  float*  csum = (float*)(ws + off);  off += (size_t)H_ * T_ * 4;
  __bf16* qh   = (__bf16*)(ws + off); off += (size_t)H_ * T_ * D_ * 2;    // 4 MB
  __bf16* kh   = (__bf16*)(ws + off); off += (size_t)KVH_ * T_ * D_ * 2;
  __bf16* vt   = (__bf16*)(ws + off); off += (size_t)KVH_ * T_ * D_ * 2;
  __bf16* xb   = (__bf16*)(ws + off); off += (size_t)T_ * C_ * 2;         // 4 MB
  __bf16* wqb  = (__bf16*)(ws + off); off += (size_t)C_ * C_ * 2;         // 2 MB
  __bf16* wkb  = (__bf16*)(ws + off); off += (size_t)256 * C_ * 2;
  __bf16* wvb  = (__bf16*)(ws + off); off += (size_t)256 * C_ * 2;
  __bf16* wob  = (__bf16*)(ws + off); off += (size_t)C_ * C_ * 2;         // 2 MB
  // attention partial accumulators -- MUST stay contiguous (zeroed as one
  // 2,129,920-float segment by cvtgates_kernel)
  float*  oacc = (float*)(ws + off);  off += (size_t)H_ * T_ * D_ * 4;    // 8 MB
  float*  lsacc= (float*)(ws + off);  off += (size_t)H_ * T_ * 4;         // 128 KB

  // 0) fp32 -> bf16 conversions + accumulator zero-init + GATES
  cvtgates_kernel<<<3344 + 512, 256, 0, stream>>>(
      x, Wq, Wk, Wv, Wo, wl, xb, wqb, wkb, wvb, wob, oacc, fgw, fgb, logf);
  // 1) QKV projection (bf16): BM=BN=BK=64, 768 blocks = 3.0/CU exact
  gemm64_kernel<<<dim3(24, 32), 256, 0, stream>>>(
      xb, 1024, 1536, wqb, 1024, wkb, 1280, wvb, qkv);
  // 2) RMSNorm + RoPE (+V direct-transposed store) + cumsum fused
  normrope_kernel<<<T_ + H_, 256, 0, stream>>>(qkv, qnw, knw, qh, kh, vt,
                                               logf, csum);
  // 3) flash attention v8 (stride-72, proven), 1024 blocks
  attn_kernel<<<NBLK_, 256, 0, stream>>>(qh, kh, vt, csum, oacc, lsacc);
  // 4) output projection with fused finalize: 512 blocks = 2.0/CU
  gemmout_kernel<<<dim3(16, 32), 256, 0, stream>>>(
      oacc, lsacc, wob, (float*)d_out);
}

// Round 18
// 180.180 us; speedup vs baseline: 1.3359x; 1.0319x over previous
//
#include <hip/hip_runtime.h>

typedef __bf16 bf16x8 __attribute__((ext_vector_type(8)));
typedef float f32x4 __attribute__((ext_vector_type(4)));

#define MFMA_BF16 __builtin_amdgcn_mfma_f32_16x16x32_bf16

static constexpr int T_ = 2048;
static constexpr int C_ = 1024;
static constexpr int H_ = 16;
static constexpr int KVH_ = 4;
static constexpr int D_ = 64;
static constexpr float INVLN2_ = 1.4426950408889634f;
static constexpr float SCALE2_ = 0.125f * 1.4426950408889634f;
// Fixed softmax shift: scores = qk*SCALE + (ci-cj) with ci-cj<=0 and
// |qk|*SCALE <= 8 (rmsnorm'd) -> row max in [-8, 8]. Shift by 10: exp args
// <= -2 (no overflow); row max term >= exp(-18) (no 0/0). Constant shift =>
// arbitrary j-partials combine by plain summation (no max bookkeeping).
static constexpr float MSHIFT_ = 10.0f;

// Uniform attention work: unit = (h, ib, jt), W = 16*528 = 8448.
// Grid = 1024 blocks exactly (4/CU); groups of 4 blocks cover 33 units
// as 9+8+8+8. LDS stride 72 (16B-aligned; R13: non-multiple-of-8 strides
// split b128 ops; R12 conflict counter at 72 is ~4us total, accepted).
static constexpr int UPH_ = 528;
static constexpr int NBLK_ = 1024;

// ---------------------------------------------------------------------------
// cvt + gates FUSED (R11). Blocks [0,3344): fp32->bf16 + accumulator zero.
// Blocks [3344,3856): gates with wl staged coalesced into LDS + transposed.
// ---------------------------------------------------------------------------
__device__ inline void cvt8(__bf16* dst, const float* src) {
  float4 a = *(const float4*)src;
  float4 b = *(const float4*)(src + 4);
  bf16x8 r;
  r[0] = (__bf16)a.x; r[1] = (__bf16)a.y; r[2] = (__bf16)a.z; r[3] = (__bf16)a.w;
  r[4] = (__bf16)b.x; r[5] = (__bf16)b.y; r[6] = (__bf16)b.z; r[7] = (__bf16)b.w;
  *(bf16x8*)dst = r;
}

__global__ __launch_bounds__(256) void cvtgates_kernel(
    const float* __restrict__ x,  const float* __restrict__ wq,
    const float* __restrict__ wk, const float* __restrict__ wv,
    const float* __restrict__ wo, const float* __restrict__ wl,
    __bf16* __restrict__ xb,  __bf16* __restrict__ wqb,
    __bf16* __restrict__ wkb, __bf16* __restrict__ wvb,
    __bf16* __restrict__ wob, float* __restrict__ zbuf,
    const float* __restrict__ fw, const float* __restrict__ fb,
    float* __restrict__ logf)
{
  __shared__ float wlds[16 * 1024];     // [h][c] transposed wl (64 KB)
  if (blockIdx.x >= 3344) {
    const int t0 = (blockIdx.x - 3344) * 4;
    const int tid = threadIdx.x, w = tid >> 6, lane = tid & 63;
    const float4* wl4 = (const float4*)wl;
#pragma unroll
    for (int j = 0; j < 16; ++j) {
      float4 f = wl4[j * 256 + tid];
      int e = (j * 256 + tid) * 4;
      int c = e >> 4, h0 = e & 15;
      wlds[(h0 + 0) * 1024 + c] = f.x;
      wlds[(h0 + 1) * 1024 + c] = f.y;
      wlds[(h0 + 2) * 1024 + c] = f.z;
      wlds[(h0 + 3) * 1024 + c] = f.w;
    }
    float xv[4][16];
#pragma unroll
    for (int tt = 0; tt < 4; ++tt)
#pragma unroll
      for (int i = 0; i < 16; ++i)
        xv[tt][i] = x[(size_t)(t0 + tt) * C_ + i * 64 + lane];
    __syncthreads();
#pragma unroll
    for (int u = 0; u < 4; ++u) {
      int h = w * 4 + u;
      float wlr[16], fwr[16];
#pragma unroll
      for (int i = 0; i < 16; ++i) {
        wlr[i] = wlds[h * 1024 + i * 64 + lane];
        fwr[i] = fw[(size_t)h * C_ + i * 64 + lane];
      }
#pragma unroll
      for (int tt = 0; tt < 4; ++tt) {
        float s1 = 0.f, s2 = 0.f;
#pragma unroll
        for (int i = 0; i < 16; ++i) {
          s1 += xv[tt][i] * wlr[i];
          s2 += xv[tt][i] * fwr[i];
        }
        for (int m = 32; m; m >>= 1) {
          s1 += __shfl_xor(s1, m);
          s2 += __shfl_xor(s2, m);
        }
        if (lane == 0) {
          float lam = (s1 > 0.f ? s1 : expm1f(s1)) + 1.0f;
          float logit = (s2 + fb[h]) * lam;
          float ls = (logit >= 0.f) ? -log1pf(expf(-logit))
                                    : (logit - log1pf(expf(logit)));
          logf[(size_t)h * T_ + t0 + tt] = ls / (lam + 1e-3f);
        }
      }
    }
    return;
  }
  size_t i8 = ((size_t)blockIdx.x * 256 + threadIdx.x) * 8;
  // segment boundaries (elements): x 2097152 | Wq 1048576 | Wk 262144 |
  // Wv 262144 | Wo 1048576 | zero 2129920
  if (i8 < 2097152)       cvt8(xb  + i8,            x  + i8);
  else if (i8 < 3145728)  cvt8(wqb + (i8-2097152),  wq + (i8-2097152));
  else if (i8 < 3407872)  cvt8(wkb + (i8-3145728),  wk + (i8-3145728));
  else if (i8 < 3670016)  cvt8(wvb + (i8-3407872),  wv + (i8-3407872));
  else if (i8 < 4718592)  cvt8(wob + (i8-3670016),  wo + (i8-3670016));
  else {
    size_t z = i8 - 4718592;
    if (z < 2129920) {
      float4 zz = {0.f, 0.f, 0.f, 0.f};
      *(float4*)(zbuf + z) = zz;
      *(float4*)(zbuf + z + 4) = zz;
    }
  }
}

// ---------------------------------------------------------------------------
// GEMM v3: BM=BN=BK=64, 4 waves each 16x64, LDS DOUBLE-BUFFER with single
// barrier per K-step (R18; attn-v7 transform: global loads for k+1 overlap
// MFMA on k; writes to buf[cur^1] are safe -- its readers finished before
// the barrier that ended the previous iteration). QKV grid 768 = 3.0/CU.
// ---------------------------------------------------------------------------
__global__ __launch_bounds__(256) void gemm64_kernel(
    const __bf16* __restrict__ A, int K, int N,
    const __bf16* __restrict__ B0, int e0,
    const __bf16* __restrict__ B1, int e1,
    const __bf16* __restrict__ B2,
    float* __restrict__ outF)
{
  __shared__ __bf16 la[2][64 * 72];
  __shared__ __bf16 lb[2][64 * 72];
  const int m0 = blockIdx.y * 64;
  const int n0 = blockIdx.x * 64;
  const __bf16* Bs; int nrel;
  if (n0 < e0)      { Bs = B0; nrel = n0; }
  else if (n0 < e1) { Bs = B1; nrel = n0 - e0; }
  else              { Bs = B2; nrel = n0 - e1; }
  const int tid = threadIdx.x;
  const int srow = tid >> 2, scol = (tid & 3) * 16;
  const __bf16* ap = A  + (size_t)(m0   + srow) * K + scol;
  const __bf16* bp = Bs + (size_t)(nrel + srow) * K + scol;
  const int w = tid >> 6, lane = tid & 63, lq = lane >> 4, ln = lane & 15;
  const int wm = w * 16;
  f32x4 acc[4] = {};
  // prologue: stage k0 = 0 into buffer 0
  {
    bf16x8 a0 = *(const bf16x8*)(ap);
    bf16x8 a1 = *(const bf16x8*)(ap + 8);
    bf16x8 b0 = *(const bf16x8*)(bp);
    bf16x8 b1 = *(const bf16x8*)(bp + 8);
    *(bf16x8*)(la[0] + srow * 72 + scol) = a0;
    *(bf16x8*)(la[0] + srow * 72 + scol + 8) = a1;
    *(bf16x8*)(lb[0] + srow * 72 + scol) = b0;
    *(bf16x8*)(lb[0] + srow * 72 + scol + 8) = b1;
  }
  __syncthreads();
  int cur = 0;
#pragma unroll 1
  for (int k0 = 0; k0 < K; k0 += 64) {
    const bool last = (k0 + 64 >= K);
    bf16x8 na0, na1, nb0, nb1;
    if (!last) {
      na0 = *(const bf16x8*)(ap + k0 + 64);
      na1 = *(const bf16x8*)(ap + k0 + 72);
      nb0 = *(const bf16x8*)(bp + k0 + 64);
      nb1 = *(const bf16x8*)(bp + k0 + 72);
    }
#pragma unroll
    for (int kk = 0; kk < 2; ++kk) {
      bf16x8 af = *(const bf16x8*)(la[cur] + (wm + ln) * 72 + kk * 32 + lq * 8);
#pragma unroll
      for (int j = 0; j < 4; ++j) {
        bf16x8 bfr = *(const bf16x8*)(lb[cur] + (j * 16 + ln) * 72 + kk * 32 + lq * 8);
        acc[j] = MFMA_BF16(af, bfr, acc[j], 0, 0, 0);
      }
    }
    if (!last) {
      *(bf16x8*)(la[cur ^ 1] + srow * 72 + scol) = na0;
      *(bf16x8*)(la[cur ^ 1] + srow * 72 + scol + 8) = na1;
      *(bf16x8*)(lb[cur ^ 1] + srow * 72 + scol) = nb0;
      *(bf16x8*)(lb[cur ^ 1] + srow * 72 + scol + 8) = nb1;
      __syncthreads();
      cur ^= 1;
    }
  }
#pragma unroll
  for (int j = 0; j < 4; ++j)
#pragma unroll
    for (int r = 0; r < 4; ++r) {
      int row = m0 + wm + lq * 4 + r;
      int col = n0 + j * 16 + ln;
      outF[(size_t)row * N + col] = acc[j][r];
    }
}

// ---------------------------------------------------------------------------
// Output GEMM v3 with FUSED attention finalize + LDS double-buffer (R18).
// A[t][c] = oacc[h][t][d]/ls[h][t]; 16-col slices stay within one head.
// Grid (16,32) = 512 blocks = 2.0/CU.
// ---------------------------------------------------------------------------
__global__ __launch_bounds__(256) void gemmout_kernel(
    const float* __restrict__ oacc, const float* __restrict__ lsacc,
    const __bf16* __restrict__ B, float* __restrict__ outF)
{
  constexpr int K = 1024, N = 1024;
  __shared__ __bf16 la[2][64 * 72];
  __shared__ __bf16 lb[2][64 * 72];
  const int m0 = blockIdx.y * 64;
  const int n0 = blockIdx.x * 64;
  const int tid = threadIdx.x;
  const int srow = tid >> 2, scol = (tid & 3) * 16;
  const int trow = m0 + srow;
  const __bf16* bp = B + (size_t)(n0 + srow) * K + scol;
  const int w = tid >> 6, lane = tid & 63, lq = lane >> 4, ln = lane & 15;
  const int wm = w * 16;
  f32x4 acc[4] = {};

  auto loadA = [&](int k0, float4& f0, float4& f1, float4& f2, float4& f3,
                   float& inv) {
    const int c = k0 + scol;            // 16 cols within one head (16 | 64)
    const int hh = c >> 6, d = c & 63;
    const float* op = oacc + ((size_t)hh * T_ + trow) * D_ + d;
    f0 = *(const float4*)(op);
    f1 = *(const float4*)(op + 4);
    f2 = *(const float4*)(op + 8);
    f3 = *(const float4*)(op + 12);
    inv = __builtin_amdgcn_rcpf(lsacc[(size_t)hh * T_ + trow]);
  };
  auto writeA = [&](int cb, float4 f0, float4 f1, float4 f2, float4 f3,
                    float inv, bf16x8 b0, bf16x8 b1) {
    bf16x8 a0, a1;
    a0[0] = (__bf16)(f0.x * inv); a0[1] = (__bf16)(f0.y * inv);
    a0[2] = (__bf16)(f0.z * inv); a0[3] = (__bf16)(f0.w * inv);
    a0[4] = (__bf16)(f1.x * inv); a0[5] = (__bf16)(f1.y * inv);
    a0[6] = (__bf16)(f1.z * inv); a0[7] = (__bf16)(f1.w * inv);
    a1[0] = (__bf16)(f2.x * inv); a1[1] = (__bf16)(f2.y * inv);
    a1[2] = (__bf16)(f2.z * inv); a1[3] = (__bf16)(f2.w * inv);
    a1[4] = (__bf16)(f3.x * inv); a1[5] = (__bf16)(f3.y * inv);
    a1[6] = (__bf16)(f3.z * inv); a1[7] = (__bf16)(f3.w * inv);
    *(bf16x8*)(la[cb] + srow * 72 + scol) = a0;
    *(bf16x8*)(la[cb] + srow * 72 + scol + 8) = a1;
    *(bf16x8*)(lb[cb] + srow * 72 + scol) = b0;
    *(bf16x8*)(lb[cb] + srow * 72 + scol + 8) = b1;
  };

  // prologue: stage k0 = 0 into buffer 0
  {
    float4 f0, f1, f2, f3; float inv;
    loadA(0, f0, f1, f2, f3, inv);
    bf16x8 b0 = *(const bf16x8*)(bp);
    bf16x8 b1 = *(const bf16x8*)(bp + 8);
    writeA(0, f0, f1, f2, f3, inv, b0, b1);
  }
  __syncthreads();
  int cur = 0;
#pragma unroll 1
  for (int k0 = 0; k0 < K; k0 += 64) {
    const bool last = (k0 + 64 >= K);
    float4 f0, f1, f2, f3; float inv;
    bf16x8 nb0, nb1;
    if (!last) {
      loadA(k0 + 64, f0, f1, f2, f3, inv);
      nb0 = *(const bf16x8*)(bp + k0 + 64);
      nb1 = *(const bf16x8*)(bp + k0 + 72);
    }
#pragma unroll
    for (int kk = 0; kk < 2; ++kk) {
      bf16x8 af = *(const bf16x8*)(la[cur] + (wm + ln) * 72 + kk * 32 + lq * 8);
#pragma unroll
      for (int j = 0; j < 4; ++j) {
        bf16x8 bfr = *(const bf16x8*)(lb[cur] + (j * 16 + ln) * 72 + kk * 32 + lq * 8);
        acc[j] = MFMA_BF16(af, bfr, acc[j], 0, 0, 0);
      }
    }
    if (!last) {
      writeA(cur ^ 1, f0, f1, f2, f3, inv, nb0, nb1);
      __syncthreads();
      cur ^= 1;
    }
  }
#pragma unroll
  for (int j = 0; j < 4; ++j)
#pragma unroll
    for (int r = 0; r < 4; ++r) {
      int row = m0 + wm + lq * 4 + r;
      int col = n0 + j * 16 + ln;
      outF[(size_t)row * N + col] = acc[j][r];
    }
}

// ---------------------------------------------------------------------------
// RMSNorm + RoPE + head split, cumsum fused as extra blocks, V written
// directly transposed vt[kvh][d][t] (R15).
// ---------------------------------------------------------------------------
__global__ __launch_bounds__(256) void normrope_kernel(
    const float* __restrict__ qkv, const float* __restrict__ qw,
    const float* __restrict__ kw, __bf16* __restrict__ qh,
    __bf16* __restrict__ kh, __bf16* __restrict__ vt,
    const float* __restrict__ logf, float* __restrict__ csum)
{
  __shared__ float qn[1024];
  __shared__ float kn[256];
  __shared__ float red[16];
  __shared__ float rc[32], rs[32];
  if (blockIdx.x >= T_) {
    // ---- cumsum along T for head h: 3-phase block scan
    const int h = blockIdx.x - T_;
    const int tid = threadIdx.x, lane = tid & 63, w = tid >> 6;
    const float* src = logf + (size_t)h * T_ + tid * 8;
    float4 a = *(const float4*)(src);
    float4 b = *(const float4*)(src + 4);
    float v[8] = {a.x, a.y, a.z, a.w, b.x, b.y, b.z, b.w};
    float t = 0.f;
#pragma unroll
    for (int j = 0; j < 8; ++j) t += v[j];
    float s = t;
#pragma unroll
    for (int d = 1; d < 64; d <<= 1) {
      float u = __shfl_up(s, d);
      if (lane >= d) s += u;
    }
    if (lane == 63) red[w] = s;
    __syncthreads();
    float prefix = 0.f;
#pragma unroll
    for (int ww = 0; ww < 3; ++ww)
      if (ww < w) prefix += red[ww];
    float run = prefix + s - t;
    float* dst = csum + (size_t)h * T_ + tid * 8;
    float4 o0, o1;
    run += v[0]; o0.x = run; run += v[1]; o0.y = run;
    run += v[2]; o0.z = run; run += v[3]; o0.w = run;
    run += v[4]; o1.x = run; run += v[5]; o1.y = run;
    run += v[6]; o1.z = run; run += v[7]; o1.w = run;
    *(float4*)dst = o0;
    *(float4*)(dst + 4) = o1;
    return;
  }
  const int t = blockIdx.x, tid = threadIdx.x;
  if (tid < 32) {
    float fr = (float)t * exp2f((float)tid * -0.41524101186404527f);
    float sn, cs;
    sincosf(fr, &sn, &cs);
    rc[tid] = cs; rs[tid] = sn;
  }
  const float* row = qkv + (size_t)t * 1536;
  float4 q4 = *(const float4*)(row + tid * 4);
  float kvl = row[1024 + tid];
  float vvl = row[1280 + tid];
  float ssq = q4.x * q4.x + q4.y * q4.y + q4.z * q4.z + q4.w * q4.w;
  float ssk = kvl * kvl;
  const int lane = tid & 63, w = tid >> 6;
  for (int m = 32; m; m >>= 1) {
    ssq += __shfl_xor(ssq, m);
    ssk += __shfl_xor(ssk, m);
  }
  if (lane == 0) { red[w] = ssq; red[8 + w] = ssk; }
  __syncthreads();
  float sq = red[0] + red[1] + red[2] + red[3];
  float sk = red[8] + red[9] + red[10] + red[11];
  float rq = rsqrtf(sq * (1.0f / 1024.f) + 1e-6f);
  float rk = rsqrtf(sk * (1.0f / 256.f) + 1e-6f);
  qn[tid * 4 + 0] = q4.x * rq * qw[tid * 4 + 0];
  qn[tid * 4 + 1] = q4.y * rq * qw[tid * 4 + 1];
  qn[tid * 4 + 2] = q4.z * rq * qw[tid * 4 + 2];
  qn[tid * 4 + 3] = q4.w * rq * qw[tid * 4 + 3];
  kn[tid] = kvl * rk * kw[tid];
  __syncthreads();
#pragma unroll
  for (int u = 0; u < 4; ++u) {
    int cidx = tid * 4 + u;
    int hh = cidx >> 6, d = cidx & 63, i = d & 31;
    float cs = rc[i], sn = rs[i];
    float val = (d < 32) ? (qn[cidx] * cs - qn[cidx + 32] * sn)
                         : (qn[cidx] * cs + qn[cidx - 32] * sn);
    qh[(size_t)hh * T_ * D_ + (size_t)t * D_ + d] = (__bf16)val;
  }
  {
    int d = tid & 63, kvhh = tid >> 6, i = d & 31;
    float cs = rc[i], sn = rs[i];
    float kval = (d < 32) ? (kn[tid] * cs - kn[tid + 32] * sn)
                          : (kn[tid] * cs + kn[tid - 32] * sn);
    kh[(size_t)kvhh * T_ * D_ + (size_t)t * D_ + d] = (__bf16)kval;
    // V direct transposed store: vt[kvh][d][t] (no rope on V)
    vt[(size_t)kvhh * D_ * T_ + (size_t)d * T_ + t] = (__bf16)vvl;
  }
}

// v_cvt_pk_bf16_f32: packs cvt(a) into low 16b, cvt(b) into high 16b.
__device__ inline unsigned cvtpk_bf16(float a, float b) {
  unsigned r;
  asm("v_cvt_pk_bf16_f32 %0, %1, %2" : "=v"(r) : "v"(a), "v"(b));
  return r;
}

// ---------------------------------------------------------------------------
// Flash attention v8 (R11, proven 44.9us): swapped QK^T (mfma(K,Q)) ->
// P[k][q=ln]; cvt_pk packed P, 4 ds_write_b64; dbuf K/V, single barrier;
// P aliased in idle K buffer; 1024 uniform blocks; stride-72 LDS.
// ---------------------------------------------------------------------------
__global__ __launch_bounds__(256, 4) void attn_kernel(
    const __bf16* __restrict__ qh, const __bf16* __restrict__ kh,
    const __bf16* __restrict__ vt, const float* __restrict__ csum,
    float* __restrict__ oacc, float* __restrict__ lsacc)
{
  const int bid = blockIdx.x;
  const int wgid = (bid & 7) * (NBLK_ / 8) + (bid >> 3);  // XCD-contiguous
  const int g4 = wgid >> 2, r4 = wgid & 3;
  const int u0 = g4 * 33 + (r4 ? 9 + (r4 - 1) * 8 : 0);
  const int cnt = r4 ? 8 : 9;
  __shared__ __bf16 kbuf[2][64 * 72];
  __shared__ __bf16 vbuf[2][64 * 72];
  const int tid = threadIdx.x;
  const int w = tid >> 6, lane = tid & 63, lq = lane >> 4, ln = lane & 15;
  const int srow = tid >> 2, scol = (tid & 3) * 16;
  bf16x8 ones;
#pragma unroll
  for (int j = 0; j < 8; ++j) ones[j] = (__bf16)1.0f;

  auto dec = [](int u, int& h, int& ib, int& jt) {
    h = u / UPH_;
    int uh = u - h * UPH_;
    int b = (int)((sqrtf((float)(8 * uh + 1)) - 1.f) * 0.5f);
    if (b * (b + 1) / 2 > uh) --b;
    if ((b + 1) * (b + 2) / 2 <= uh) ++b;
    ib = b; jt = uh - b * (b + 1) / 2;
  };

  int h, ib, jt;
  dec(u0, h, ib, jt);
  int kvh = h >> 2;

  bf16x8 aq0, aq1;
  float ci2;                            // (csum[q] - MSHIFT) * INVLN2, q = ln
  f32x4 o[4] = {};
  f32x4 ls = {0.f, 0.f, 0.f, 0.f};
  auto loadQ = [&](int h_, int i0_) {
    const __bf16* qp = qh + ((size_t)h_ * T_ + i0_ + w * 16 + ln) * D_;
    aq0 = *(const bf16x8*)(qp + lq * 8);
    aq1 = *(const bf16x8*)(qp + 32 + lq * 8);
    ci2 = (csum[(size_t)h_ * T_ + i0_ + w * 16 + ln] - MSHIFT_) * INVLN2_;
#pragma unroll
    for (int dd = 0; dd < 4; ++dd) o[dd] = f32x4{0.f, 0.f, 0.f, 0.f};
    ls = f32x4{0.f, 0.f, 0.f, 0.f};
  };
  loadQ(h, ib * 64);

  auto fetchRegs = [&](int kvh_, int jt_, bf16x8& k0, bf16x8& k1,
                       bf16x8& v0, bf16x8& v1) {
    const __bf16* kb = kh + (size_t)kvh_ * T_ * D_;   // [t][d]
    const __bf16* vb = vt + (size_t)kvh_ * D_ * T_;   // [d][t]
    k0 = *(const bf16x8*)(kb + (size_t)(jt_ * 64 + srow) * D_ + scol);
    k1 = *(const bf16x8*)(kb + (size_t)(jt_ * 64 + srow) * D_ + scol + 8);
    v0 = *(const bf16x8*)(vb + (size_t)srow * T_ + jt_ * 64 + scol);
    v1 = *(const bf16x8*)(vb + (size_t)srow * T_ + jt_ * 64 + scol + 8);
  };
  auto writeStage = [&](int cb, bf16x8 k0, bf16x8 k1, bf16x8 v0, bf16x8 v1) {
    *(bf16x8*)(kbuf[cb] + srow * 72 + scol) = k0;
    *(bf16x8*)(kbuf[cb] + srow * 72 + scol + 8) = k1;
    *(bf16x8*)(vbuf[cb] + srow * 72 + scol) = v0;
    *(bf16x8*)(vbuf[cb] + srow * 72 + scol + 8) = v1;
  };

  auto tilebody = [&](int cb, int j0, bool diag) {
    const __bf16* kt = kbuf[cb];
    const __bf16* vtt = vbuf[cb];
    __bf16* pw = kbuf[cb ^ 1] + w * 16 * 72;   // aliased P scratch (dead K)
    f32x4 cj2[4];
#pragma unroll
    for (int jj = 0; jj < 4; ++jj) {
      float4 c4 = *(const float4*)(csum + (size_t)h * T_ + j0 + jj * 16 + lq * 4);
      cj2[jj] = f32x4{c4.x * INVLN2_, c4.y * INVLN2_,
                      c4.z * INVLN2_, c4.w * INVLN2_};
    }
    f32x4 s[4];
    const f32x4 zf = {0.f, 0.f, 0.f, 0.f};
    __builtin_amdgcn_s_setprio(1);
#pragma unroll
    for (int jj = 0; jj < 4; ++jj) {
      bf16x8 bk0 = *(const bf16x8*)(kt + (jj * 16 + ln) * 72 + lq * 8);
      bf16x8 bk1 = *(const bf16x8*)(kt + (jj * 16 + ln) * 72 + 32 + lq * 8);
      // SWAPPED: A = K rows, B = Q -> D[k][q=ln]
      s[jj] = MFMA_BF16(bk0, aq0, zf, 0, 0, 0);
      s[jj] = MFMA_BF16(bk1, aq1, s[jj], 0, 0, 0);
    }
    __builtin_amdgcn_s_setprio(0);
    bf16x8 bv0[4], bv1[4];
#pragma unroll
    for (int dd = 0; dd < 4; ++dd) {
      bv0[dd] = *(const bf16x8*)(vtt + (dd * 16 + ln) * 72 + lq * 8);
      bv1[dd] = *(const bf16x8*)(vtt + (dd * 16 + ln) * 72 + 32 + lq * 8);
    }
    const int qloc = w * 16 + ln;
#pragma unroll
    for (int jj = 0; jj < 4; ++jj) {
      float p[4];
#pragma unroll
      for (int r = 0; r < 4; ++r) {
        float arg = fmaf(s[jj][r], SCALE2_, ci2 - cj2[jj][r]);
        p[r] = exp2f(arg);
        if (diag && (jj * 16 + lq * 4 + r > qloc)) p[r] = 0.f;
      }
      unsigned lo = cvtpk_bf16(p[0], p[1]);
      unsigned hi = cvtpk_bf16(p[2], p[3]);
      uint2 pr; pr.x = lo; pr.y = hi;
      *(uint2*)(pw + ln * 72 + jj * 16 + lq * 4) = pr;
    }
    asm volatile("s_waitcnt lgkmcnt(0)" ::: "memory");
    bf16x8 pa0 = *(const bf16x8*)(pw + ln * 72 + lq * 8);
    bf16x8 pa1 = *(const bf16x8*)(pw + ln * 72 + 32 + lq * 8);
    __builtin_amdgcn_s_setprio(1);
    ls = MFMA_BF16(pa0, ones, ls, 0, 0, 0);
    ls = MFMA_BF16(pa1, ones, ls, 0, 0, 0);
#pragma unroll
    for (int dd = 0; dd < 4; ++dd) {
      o[dd] = MFMA_BF16(pa0, bv0[dd], o[dd], 0, 0, 0);
      o[dd] = MFMA_BF16(pa1, bv1[dd], o[dd], 0, 0, 0);
    }
    __builtin_amdgcn_s_setprio(0);
  };

  auto flush = [&]() {
    const int i0 = ib * 64;
#pragma unroll
    for (int dd = 0; dd < 4; ++dd)
#pragma unroll
      for (int r = 0; r < 4; ++r) {
        int iabs = i0 + w * 16 + lq * 4 + r;
        atomicAdd(oacc + ((size_t)h * T_ + iabs) * D_ + dd * 16 + ln,
                  o[dd][r]);
      }
    if (ln == 0) {
#pragma unroll
      for (int r = 0; r < 4; ++r)
        atomicAdd(lsacc + (size_t)h * T_ + ib * 64 + w * 16 + lq * 4 + r,
                  ls[r]);
    }
  };

  {
    bf16x8 k0, k1, v0, v1;
    fetchRegs(kvh, jt, k0, k1, v0, v1);
    writeStage(0, k0, k1, v0, v1);
  }
  __syncthreads();

  int cur = 0;
#pragma unroll 1
  for (int s = 0; s < cnt; ++s) {
    const bool last = (s == cnt - 1);
    int nh = 0, nib = 0, njt = 0;
    bf16x8 k0, k1, v0, v1;
    if (!last) {
      dec(u0 + s + 1, nh, nib, njt);
      fetchRegs(nh >> 2, njt, k0, k1, v0, v1);   // overlaps tilebody below
    }
    tilebody(cur, jt * 64, jt == ib);
    if (!last) writeStage(cur ^ 1, k0, k1, v0, v1);  // own wave slice only
    const bool rowEnd = last || nib != ib || nh != h;
    if (rowEnd) flush();                             // atomics overlap barrier
    if (!last) {
      __syncthreads();   // single barrier: buf[cur^1] now staged + visible
      if (nh != h || nib != ib) loadQ(nh, nib * 64);
      h = nh; ib = nib; jt = njt; kvh = nh >> 2;
      cur ^= 1;
    }
  }
}

// ---------------------------------------------------------------------------
extern "C" void kernel_launch(void* const* d_in, const int* in_sizes, int n_in,
                              void* d_out, int out_size, void* d_ws, size_t ws_size,
                              hipStream_t stream) {
  const float* x   = (const float*)d_in[0];
  const float* Wq  = (const float*)d_in[1];
  const float* Wk  = (const float*)d_in[2];
  const float* Wv  = (const float*)d_in[3];
  const float* Wo  = (const float*)d_in[4];
  const float* qnw = (const float*)d_in[5];
  const float* knw = (const float*)d_in[6];
  const float* fgw = (const float*)d_in[7];
  const float* fgb = (const float*)d_in[8];
  const float* wl  = (const float*)d_in[9];

  char* ws = (char*)d_ws;
  size_t off = 0;
  float*  qkv  = (float*)(ws + off);  off += (size_t)T_ * 1536 * 4;       // 12.6 MB
  float*  logf = (float*)(ws + off);  off += (size_t)H_ * T_ * 4;
  float*  csum = (float*)(ws + off);  off += (size_t)H_ * T_ * 4;
  __bf16* qh   = (__bf16*)(ws + off); off += (size_t)H_ * T_ * D_ * 2;    // 4 MB
  __bf16* kh   = (__bf16*)(ws + off); off += (size_t)KVH_ * T_ * D_ * 2;
  __bf16* vt   = (__bf16*)(ws + off); off += (size_t)KVH_ * T_ * D_ * 2;
  __bf16* xb   = (__bf16*)(ws + off); off += (size_t)T_ * C_ * 2;         // 4 MB
  __bf16* wqb  = (__bf16*)(ws + off); off += (size_t)C_ * C_ * 2;         // 2 MB
  __bf16* wkb  = (__bf16*)(ws + off); off += (size_t)256 * C_ * 2;
  __bf16* wvb  = (__bf16*)(ws + off); off += (size_t)256 * C_ * 2;
  __bf16* wob  = (__bf16*)(ws + off); off += (size_t)C_ * C_ * 2;         // 2 MB
  // attention partial accumulators -- MUST stay contiguous (zeroed as one
  // 2,129,920-float segment by cvtgates_kernel)
  float*  oacc = (float*)(ws + off);  off += (size_t)H_ * T_ * D_ * 4;    // 8 MB
  float*  lsacc= (float*)(ws + off);  off += (size_t)H_ * T_ * 4;         // 128 KB

  // 0) fp32 -> bf16 conversions + accumulator zero-init + GATES
  cvtgates_kernel<<<3344 + 512, 256, 0, stream>>>(
      x, Wq, Wk, Wv, Wo, wl, xb, wqb, wkb, wvb, wob, oacc, fgw, fgb, logf);
  // 1) QKV projection (bf16): dbuf BM=BN=BK=64, 768 blocks = 3.0/CU
  gemm64_kernel<<<dim3(24, 32), 256, 0, stream>>>(
      xb, 1024, 1536, wqb, 1024, wkb, 1280, wvb, qkv);
  // 2) RMSNorm + RoPE (+V direct-transposed store) + cumsum fused
  normrope_kernel<<<T_ + H_, 256, 0, stream>>>(qkv, qnw, knw, qh, kh, vt,
                                               logf, csum);
  // 3) flash attention v8 (stride-72, proven), 1024 blocks
  attn_kernel<<<NBLK_, 256, 0, stream>>>(qh, kh, vt, csum, oacc, lsacc);
  // 4) output projection, fused finalize, dbuf: 512 blocks = 2.0/CU
  gemmout_kernel<<<dim3(16, 32), 256, 0, stream>>>(
      oacc, lsacc, wob, (float*)d_out);
}